// Round 3
// baseline (603.935 us; speedup 1.0000x reference)
//
#include <hip/hip_runtime.h>
#include <hip/hip_bf16.h>
#include <stdint.h>

typedef __bf16 bf16_8 __attribute__((ext_vector_type(8)));
typedef float f32x4 __attribute__((ext_vector_type(4)));

#define AS1 __attribute__((address_space(1)))
#define AS3 __attribute__((address_space(3)))

__device__ __forceinline__ void gload_lds16(const void* g, void* l) {
  __builtin_amdgcn_global_load_lds((const AS1 void*)g, (AS3 void*)l, 16, 0, 0);
}

// ---------------------------------------------------------------------------
// Dtype detection: cos[0][i] == 1.0 exactly. f32 1.0 low halfword = 0x0000,
// bf16 pair (1.0,1.0) = 0x3F803F80 -> low halfword 0x3F80.
// ---------------------------------------------------------------------------
__global__ void detect_dtype(const void* __restrict__ cosT, int* __restrict__ flag) {
  uint32_t w = *reinterpret_cast<const uint32_t*>(cosT);
  *flag = ((w & 0xFFFFu) == 0x3F80u) ? 1 : 0;   // 1 = bf16 buffers, 0 = f32
}

// x (or any flat array) -> bf16, 8 elems per thread
__global__ __launch_bounds__(256) void to_bf16_vec(const void* __restrict__ src,
                                                   __bf16* __restrict__ dst,
                                                   int n8, const int* __restrict__ flag) {
  const int i = blockIdx.x * 256 + threadIdx.x;
  if (i >= n8) return;
  if (*flag) {
    reinterpret_cast<int4*>(dst)[i] = reinterpret_cast<const int4*>(src)[i];
  } else {
    const float4* s = reinterpret_cast<const float4*>(src);
    const float4 a = s[2 * i], b = s[2 * i + 1];
    __bf16 o[8] = {(__bf16)a.x, (__bf16)a.y, (__bf16)a.z, (__bf16)a.w,
                   (__bf16)b.x, (__bf16)b.y, (__bf16)b.z, (__bf16)b.w};
    reinterpret_cast<int4*>(dst)[i] = *reinterpret_cast<int4*>(o);
  }
}

// cos & sin tables -> f32 scratch (csF[0..n) = cos, csF[n..2n) = sin)
__global__ __launch_bounds__(256) void tables_to_f32(const void* __restrict__ c,
                                                     const void* __restrict__ s,
                                                     float* __restrict__ dst, int n,
                                                     const int* __restrict__ flag) {
  const int i = blockIdx.x * 256 + threadIdx.x;
  if (i >= n) return;
  if (*flag) {
    dst[i]     = (float)reinterpret_cast<const __bf16*>(c)[i];
    dst[n + i] = (float)reinterpret_cast<const __bf16*>(s)[i];
  } else {
    dst[i]     = reinterpret_cast<const float*>(c)[i];
    dst[n + i] = reinterpret_cast<const float*>(s)[i];
  }
}

// ---------------------------------------------------------------------------
// Transpose + convert: src (R x C, f32 or bf16) -> dst (C x R, bf16)
// grid (C/32, R/32), block (32,8)
// ---------------------------------------------------------------------------
__global__ void transpose_to_bf16(const void* __restrict__ src, __bf16* __restrict__ dst,
                                  int R, int C, const int* __restrict__ flag) {
  __shared__ __bf16 t[32][33];
  const int c0 = blockIdx.x * 32, r0 = blockIdx.y * 32;
  const bool isb = (*flag != 0);
  #pragma unroll
  for (int i = 0; i < 32; i += 8) {
    const size_t idx = (size_t)(r0 + threadIdx.y + i) * C + c0 + threadIdx.x;
    t[threadIdx.y + i][threadIdx.x] =
        isb ? reinterpret_cast<const __bf16*>(src)[idx]
            : (__bf16)reinterpret_cast<const float*>(src)[idx];
  }
  __syncthreads();
  #pragma unroll
  for (int i = 0; i < 32; i += 8)
    dst[(size_t)(c0 + threadIdx.y + i) * R + r0 + threadIdx.x] = t[threadIdx.x][threadIdx.y + i];
}

// ---------------------------------------------------------------------------
// GEMM: C(MxN) = A(MxK) * Bt(NxK)^T, bf16 in, f32 accum. 128x128 tile, BK=64,
// 4 waves (2x2), each wave 64x64 via 4x4 16x16x32 MFMA frags. m97 structure.
// DYN=1: store f32 or bf16 to Cv per *flag. DYN=0: store bf16.
// ---------------------------------------------------------------------------
template <int DYN>
__global__ __launch_bounds__(256) void gemm_bt_t(const __bf16* __restrict__ A,
                                                 const __bf16* __restrict__ Bt,
                                                 void* __restrict__ Cv,
                                                 int M, int N, int K,
                                                 const int* __restrict__ flag) {
  __shared__ __attribute__((aligned(16))) __bf16 As[128][64];
  __shared__ __attribute__((aligned(16))) __bf16 Bs[128][64];
  const int tid = threadIdx.x;
  const int lane = tid & 63;
  const int w = tid >> 6;
  const int wr = (w >> 1) * 64;
  const int wc = (w & 1) * 64;
  const int bm = blockIdx.x * 128;
  const int bn = blockIdx.y * 128;
  const int r = lane & 15, g = lane >> 4;
  const bool isb = DYN ? (*flag != 0) : true;

  f32x4 acc[4][4] = {};

  for (int k0 = 0; k0 < K; k0 += 64) {
    __syncthreads();
    #pragma unroll
    for (int i = 0; i < 4; ++i) {
      const int off = tid * 16 + i * 4096;   // byte offset into 16KB tile
      const int row = off >> 7;              // 128 B per row
      const int col = (off & 127) >> 1;      // element col
      gload_lds16(A + (size_t)(bm + row) * K + k0 + col, (char*)&As[0][0] + off);
      gload_lds16(Bt + (size_t)(bn + row) * K + k0 + col, (char*)&Bs[0][0] + off);
    }
    __syncthreads();
    #pragma unroll
    for (int kk = 0; kk < 64; kk += 32) {
      bf16_8 af[4], bfr[4];
      #pragma unroll
      for (int m = 0; m < 4; ++m)
        af[m] = *reinterpret_cast<const bf16_8*>(&As[wr + m * 16 + r][kk + g * 8]);
      #pragma unroll
      for (int n = 0; n < 4; ++n)
        bfr[n] = *reinterpret_cast<const bf16_8*>(&Bs[wc + n * 16 + r][kk + g * 8]);
      #pragma unroll
      for (int m = 0; m < 4; ++m)
        #pragma unroll
        for (int n = 0; n < 4; ++n)
          acc[m][n] = __builtin_amdgcn_mfma_f32_16x16x32_bf16(af[m], bfr[n], acc[m][n], 0, 0, 0);
    }
  }

  #pragma unroll
  for (int m = 0; m < 4; ++m)
    #pragma unroll
    for (int n = 0; n < 4; ++n)
      #pragma unroll
      for (int j = 0; j < 4; ++j) {
        const int row = bm + wr + m * 16 + g * 4 + j;
        const int col = bn + wc + n * 16 + r;
        const float v = acc[m][n][j];
        if (isb) reinterpret_cast<__bf16*>(Cv)[(size_t)row * N + col] = (__bf16)v;
        else     reinterpret_cast<float*>(Cv)[(size_t)row * N + col] = v;
      }
}

// ---------------------------------------------------------------------------
// RoPE + RMSNorm in-place on Q (heads 0..15) and K (heads 16..19) of QKV
// (4096 x 3072). One wave per (row m, head), 4 waves/block. csF = f32 tables.
// ---------------------------------------------------------------------------
__global__ __launch_bounds__(256) void rope_rms(__bf16* __restrict__ qkv,
                                                const float* __restrict__ csF) {
  const int gw = blockIdx.x * 4 + (threadIdx.x >> 6);
  const int lane = threadIdx.x & 63;
  const int head = gw % 20;            // 0..15 = Q heads, 16..19 = K heads
  const int m = gw / 20;               // 0..4095
  const int t = m & 2047;              // position within T
  __bf16* p = qkv + (size_t)m * 3072 + head * 128;
  const float x1 = (float)p[lane];
  const float x2 = (float)p[lane + 64];
  const float c = csF[t * 64 + lane];
  const float s = csF[131072 + t * 64 + lane];
  const float y1 = x1 * c + x2 * s;
  const float y2 = x2 * c - x1 * s;
  float ss = y1 * y1 + y2 * y2;
  #pragma unroll
  for (int mk = 32; mk >= 1; mk >>= 1) ss += __shfl_xor(ss, mk, 64);
  const float inv = rsqrtf(ss * (1.0f / 128.0f) + 1.1920929e-7f);
  p[lane] = (__bf16)(y1 * inv);
  p[lane + 64] = (__bf16)(y2 * inv);
}

// ---------------------------------------------------------------------------
// GQA causal flash attention. grid (T/64, B*16). 4 waves, wave w owns q rows
// [qt*64 + w*16, +16). KV tiles of 32 in LDS (K linear+pad, V transposed).
// Online softmax f32; P routed D-layout -> A-layout via per-wave LDS scratch.
// ---------------------------------------------------------------------------
__global__ __launch_bounds__(256) void attn_fwd(const __bf16* __restrict__ qkv,
                                                __bf16* __restrict__ out, int T) {
  __shared__ __attribute__((aligned(16))) __bf16 Kl[32][136];
  __shared__ __attribute__((aligned(16))) __bf16 Vt[128][40];
  __shared__ __attribute__((aligned(16))) __bf16 Pl[4][16][40];

  const int tid = threadIdx.x, lane = tid & 63, w = tid >> 6;
  const int r = lane & 15, g = lane >> 4;
  const int qt = blockIdx.x;
  const int bh = blockIdx.y;
  const int b = bh >> 4, h = bh & 15;
  const int kvh = h >> 2;
  const int qrow0 = qt * 64 + w * 16;

  bf16_8 qf[4];
  {
    const int t = qrow0 + r;
    const __bf16* qp = qkv + (size_t)(b * T + t) * 3072 + h * 128 + g * 8;
    #pragma unroll
    for (int kb = 0; kb < 4; ++kb)
      qf[kb] = *reinterpret_cast<const bf16_8*>(qp + kb * 32);
  }

  f32x4 accO[8] = {};
  float mst[4], lst[4];
  #pragma unroll
  for (int j = 0; j < 4; ++j) { mst[j] = -1e30f; lst[j] = 0.0f; }

  const float scale = 0.08838834764831845f;  // 1/sqrt(128)
  const int ntiles = (qt + 1) * 2;

  const __bf16* Kbase = qkv + (size_t)(b * T) * 3072 + 2048 + kvh * 128;
  const __bf16* Vbase = qkv + (size_t)(b * T) * 3072 + 2560 + kvh * 128;

  for (int kt = 0; kt < ntiles; ++kt) {
    __syncthreads();
    #pragma unroll
    for (int i = 0; i < 2; ++i) {
      const int off = tid * 8 + i * 2048;  // element offset, 8 elems per chunk
      const int row = off >> 7;            // 0..31
      const int col = off & 127;
      const int kv = kt * 32 + row;
      const int4 kd = *reinterpret_cast<const int4*>(Kbase + (size_t)kv * 3072 + col);
      *reinterpret_cast<int4*>(&Kl[row][col]) = kd;
      const int4 vd = *reinterpret_cast<const int4*>(Vbase + (size_t)kv * 3072 + col);
      const __bf16* ve = reinterpret_cast<const __bf16*>(&vd);
      #pragma unroll
      for (int j = 0; j < 8; ++j) Vt[col + j][row] = ve[j];
    }
    __syncthreads();

    f32x4 sacc[2] = {};
    #pragma unroll
    for (int kb = 0; kb < 4; ++kb)
      #pragma unroll
      for (int n = 0; n < 2; ++n) {
        const bf16_8 kf = *reinterpret_cast<const bf16_8*>(&Kl[n * 16 + r][kb * 32 + g * 8]);
        sacc[n] = __builtin_amdgcn_mfma_f32_16x16x32_bf16(qf[kb], kf, sacc[n], 0, 0, 0);
      }

    float pvv[2][4], pm[4];
    #pragma unroll
    for (int j = 0; j < 4; ++j) {
      const int qpos = qrow0 + g * 4 + j;
      float s0 = sacc[0][j] * scale;
      float s1 = sacc[1][j] * scale;
      if (kt * 32 + r > qpos) s0 = -1e30f;
      if (kt * 32 + 16 + r > qpos) s1 = -1e30f;
      pvv[0][j] = s0; pvv[1][j] = s1;
      float mx = fmaxf(s0, s1);
      mx = fmaxf(mx, __shfl_xor(mx, 1, 64));
      mx = fmaxf(mx, __shfl_xor(mx, 2, 64));
      mx = fmaxf(mx, __shfl_xor(mx, 4, 64));
      mx = fmaxf(mx, __shfl_xor(mx, 8, 64));
      pm[j] = mx;
    }
    float alpha[4];
    #pragma unroll
    for (int j = 0; j < 4; ++j) {
      const float mn = fmaxf(mst[j], pm[j]);
      alpha[j] = __expf(mst[j] - mn);
      mst[j] = mn;
      const float p0 = __expf(pvv[0][j] - mn);
      const float p1 = __expf(pvv[1][j] - mn);
      pvv[0][j] = p0; pvv[1][j] = p1;
      float rs = p0 + p1;
      rs += __shfl_xor(rs, 1, 64);
      rs += __shfl_xor(rs, 2, 64);
      rs += __shfl_xor(rs, 4, 64);
      rs += __shfl_xor(rs, 8, 64);
      lst[j] = lst[j] * alpha[j] + rs;
    }
    #pragma unroll
    for (int n = 0; n < 2; ++n)
      #pragma unroll
      for (int j = 0; j < 4; ++j)
        Pl[w][g * 4 + j][n * 16 + r] = (__bf16)pvv[n][j];
    #pragma unroll
    for (int dt = 0; dt < 8; ++dt)
      #pragma unroll
      for (int j = 0; j < 4; ++j)
        accO[dt][j] *= alpha[j];
    const bf16_8 pf = *reinterpret_cast<const bf16_8*>(&Pl[w][r][g * 8]);
    #pragma unroll
    for (int dt = 0; dt < 8; ++dt) {
      const bf16_8 vf = *reinterpret_cast<const bf16_8*>(&Vt[dt * 16 + r][g * 8]);
      accO[dt] = __builtin_amdgcn_mfma_f32_16x16x32_bf16(pf, vf, accO[dt], 0, 0, 0);
    }
  }

  float inv[4];
  #pragma unroll
  for (int j = 0; j < 4; ++j) inv[j] = 1.0f / lst[j];
  #pragma unroll
  for (int dt = 0; dt < 8; ++dt)
    #pragma unroll
    for (int j = 0; j < 4; ++j) {
      const int t = qrow0 + g * 4 + j;
      out[(size_t)(b * T + t) * 2048 + h * 128 + dt * 16 + r] = (__bf16)(accO[dt][j] * inv[j]);
    }
}

// ---------------------------------------------------------------------------
extern "C" void kernel_launch(void* const* d_in, const int* in_sizes, int n_in,
                              void* d_out, int out_size, void* d_ws, size_t ws_size,
                              hipStream_t stream) {
  const void* x    = d_in[0];
  const void* cosT = d_in[1];
  const void* sinT = d_in[2];
  const void* W_Q  = d_in[3];
  const void* W_K  = d_in[4];
  const void* W_V  = d_in[5];
  const void* W_O  = d_in[6];

  const int B = 2, T = 2048, C = 2048;
  const int M = B * T;        // 4096
  const int NQKV = 3072;

  char* ws = (char*)d_ws;
  int*    flag = (int*)ws;                       ws += 256;
  float*  csF  = (float*)ws;                     ws += (size_t)2 * 131072 * 4;   // 1 MB
  __bf16* xb   = (__bf16*)ws;                    ws += (size_t)M * C * 2;        // 16.8 MB
  __bf16* Wt   = (__bf16*)ws;                    ws += (size_t)NQKV * C * 2;     // 12.6 MB
  __bf16* WOt  = (__bf16*)ws;                    ws += (size_t)C * C * 2;        // 8.4 MB
  __bf16* QKV  = (__bf16*)ws;                    ws += (size_t)M * NQKV * 2;     // 25.2 MB
  __bf16* AO   = (__bf16*)ws;                    ws += (size_t)M * C * 2;        // 16.8 MB

  detect_dtype<<<1, 1, 0, stream>>>(cosT, flag);
  tables_to_f32<<<131072 / 256, 256, 0, stream>>>(cosT, sinT, csF, 131072, flag);
  to_bf16_vec<<<(M * C / 8) / 256, 256, 0, stream>>>(x, xb, M * C / 8, flag);

  dim3 tb(32, 8);
  transpose_to_bf16<<<dim3(2048 / 32, 2048 / 32), tb, 0, stream>>>(W_Q, Wt, 2048, 2048, flag);
  transpose_to_bf16<<<dim3(512 / 32, 2048 / 32), tb, 0, stream>>>(W_K, Wt + (size_t)2048 * 2048, 2048, 512, flag);
  transpose_to_bf16<<<dim3(512 / 32, 2048 / 32), tb, 0, stream>>>(W_V, Wt + (size_t)2560 * 2048, 2048, 512, flag);
  transpose_to_bf16<<<dim3(2048 / 32, 2048 / 32), tb, 0, stream>>>(W_O, WOt, 2048, 2048, flag);

  gemm_bt_t<0><<<dim3(M / 128, NQKV / 128), 256, 0, stream>>>(xb, Wt, QKV, M, NQKV, C, flag);
  rope_rms<<<dim3(M * 20 / 4), 256, 0, stream>>>(QKV, csF);
  attn_fwd<<<dim3(T / 64, B * 16), 256, 0, stream>>>(QKV, AO, T);
  gemm_bt_t<1><<<dim3(M / 128, C / 128), 256, 0, stream>>>(AO, WOt, d_out, M, C, C, flag);
}

// Round 5
// 271.476 us; speedup vs baseline: 2.2246x; 2.2246x over previous
//
#include <hip/hip_runtime.h>
#include <hip/hip_bf16.h>
#include <stdint.h>

typedef __bf16 bf16_4 __attribute__((ext_vector_type(4)));
typedef __bf16 bf16_8 __attribute__((ext_vector_type(8)));
typedef float f32x4 __attribute__((ext_vector_type(4)));

#define AS1 __attribute__((address_space(1)))
#define AS3 __attribute__((address_space(3)))

__device__ __forceinline__ void gload_lds16(const void* g, void* l) {
  __builtin_amdgcn_global_load_lds((const AS1 void*)g, (AS3 void*)l, 16, 0, 0);
}

// ---------------------------------------------------------------------------
// Dtype detection: cos[0][i] == 1.0 exactly. f32 1.0 low halfword = 0x0000,
// bf16 pair (1.0,1.0) = 0x3F803F80 -> low halfword 0x3F80.
// ---------------------------------------------------------------------------
__global__ void detect_dtype(const void* __restrict__ cosT, int* __restrict__ flag) {
  uint32_t w = *reinterpret_cast<const uint32_t*>(cosT);
  *flag = ((w & 0xFFFFu) == 0x3F80u) ? 1 : 0;   // 1 = bf16 buffers, 0 = f32
}

__global__ __launch_bounds__(256) void to_bf16_vec(const void* __restrict__ src,
                                                   __bf16* __restrict__ dst,
                                                   int n8, const int* __restrict__ flag) {
  const int i = blockIdx.x * 256 + threadIdx.x;
  if (i >= n8) return;
  if (*flag) {
    reinterpret_cast<int4*>(dst)[i] = reinterpret_cast<const int4*>(src)[i];
  } else {
    const float4* s = reinterpret_cast<const float4*>(src);
    const float4 a = s[2 * i], b = s[2 * i + 1];
    __bf16 o[8] = {(__bf16)a.x, (__bf16)a.y, (__bf16)a.z, (__bf16)a.w,
                   (__bf16)b.x, (__bf16)b.y, (__bf16)b.z, (__bf16)b.w};
    reinterpret_cast<int4*>(dst)[i] = *reinterpret_cast<int4*>(o);
  }
}

__global__ __launch_bounds__(256) void tables_to_f32(const void* __restrict__ c,
                                                     const void* __restrict__ s,
                                                     float* __restrict__ dst, int n,
                                                     const int* __restrict__ flag) {
  const int i = blockIdx.x * 256 + threadIdx.x;
  if (i >= n) return;
  if (*flag) {
    dst[i]     = (float)reinterpret_cast<const __bf16*>(c)[i];
    dst[n + i] = (float)reinterpret_cast<const __bf16*>(s)[i];
  } else {
    dst[i]     = reinterpret_cast<const float*>(c)[i];
    dst[n + i] = reinterpret_cast<const float*>(s)[i];
  }
}

// ---------------------------------------------------------------------------
// Transpose + convert: src (R x C, f32 or bf16) -> dst (C x R, bf16)
// ---------------------------------------------------------------------------
__global__ void transpose_to_bf16(const void* __restrict__ src, __bf16* __restrict__ dst,
                                  int R, int C, const int* __restrict__ flag) {
  __shared__ __bf16 t[32][33];
  const int c0 = blockIdx.x * 32, r0 = blockIdx.y * 32;
  const bool isb = (*flag != 0);
  #pragma unroll
  for (int i = 0; i < 32; i += 8) {
    const size_t idx = (size_t)(r0 + threadIdx.y + i) * C + c0 + threadIdx.x;
    t[threadIdx.y + i][threadIdx.x] =
        isb ? reinterpret_cast<const __bf16*>(src)[idx]
            : (__bf16)reinterpret_cast<const float*>(src)[idx];
  }
  __syncthreads();
  #pragma unroll
  for (int i = 0; i < 32; i += 8)
    dst[(size_t)(c0 + threadIdx.y + i) * R + r0 + threadIdx.x] = t[threadIdx.x][threadIdx.y + i];
}

// ---------------------------------------------------------------------------
// V slice of QKV -> VT [b][kvh][d][t]  (bf16 tiled transpose)
// grid (T/32, 512/32, B), block (32,8)
// ---------------------------------------------------------------------------
__global__ void vtrans(const __bf16* __restrict__ qkv, __bf16* __restrict__ vt) {
  __shared__ __bf16 t[32][33];
  const int b = blockIdx.z;
  const int t0 = blockIdx.x * 32, c0 = blockIdx.y * 32;
  #pragma unroll
  for (int i = 0; i < 32; i += 8)
    t[threadIdx.y + i][threadIdx.x] =
        qkv[(size_t)(b * 2048 + t0 + threadIdx.y + i) * 3072 + 2560 + c0 + threadIdx.x];
  __syncthreads();
  #pragma unroll
  for (int i = 0; i < 32; i += 8)
    vt[(size_t)(b * 512 + c0 + threadIdx.y + i) * 2048 + t0 + threadIdx.x] =
        t[threadIdx.x][threadIdx.y + i];
}

// ---------------------------------------------------------------------------
// GEMM: C(MxN) = A(MxK) * Bt(NxK)^T, bf16 in, f32 accum. m97 structure.
// ---------------------------------------------------------------------------
template <int DYN>
__global__ __launch_bounds__(256) void gemm_bt_t(const __bf16* __restrict__ A,
                                                 const __bf16* __restrict__ Bt,
                                                 void* __restrict__ Cv,
                                                 int M, int N, int K,
                                                 const int* __restrict__ flag) {
  __shared__ __attribute__((aligned(16))) __bf16 As[128][64];
  __shared__ __attribute__((aligned(16))) __bf16 Bs[128][64];
  const int tid = threadIdx.x;
  const int lane = tid & 63;
  const int w = tid >> 6;
  const int wr = (w >> 1) * 64;
  const int wc = (w & 1) * 64;
  const int bm = blockIdx.x * 128;
  const int bn = blockIdx.y * 128;
  const int r = lane & 15, g = lane >> 4;
  const bool isb = DYN ? (*flag != 0) : true;

  f32x4 acc[4][4] = {};

  for (int k0 = 0; k0 < K; k0 += 64) {
    __syncthreads();
    #pragma unroll
    for (int i = 0; i < 4; ++i) {
      const int off = tid * 16 + i * 4096;
      const int row = off >> 7;
      const int col = (off & 127) >> 1;
      gload_lds16(A + (size_t)(bm + row) * K + k0 + col, (char*)&As[0][0] + off);
      gload_lds16(Bt + (size_t)(bn + row) * K + k0 + col, (char*)&Bs[0][0] + off);
    }
    __syncthreads();
    #pragma unroll
    for (int kk = 0; kk < 64; kk += 32) {
      bf16_8 af[4], bfr[4];
      #pragma unroll
      for (int m = 0; m < 4; ++m)
        af[m] = *reinterpret_cast<const bf16_8*>(&As[wr + m * 16 + r][kk + g * 8]);
      #pragma unroll
      for (int n = 0; n < 4; ++n)
        bfr[n] = *reinterpret_cast<const bf16_8*>(&Bs[wc + n * 16 + r][kk + g * 8]);
      #pragma unroll
      for (int m = 0; m < 4; ++m)
        #pragma unroll
        for (int n = 0; n < 4; ++n)
          acc[m][n] = __builtin_amdgcn_mfma_f32_16x16x32_bf16(af[m], bfr[n], acc[m][n], 0, 0, 0);
    }
  }

  #pragma unroll
  for (int m = 0; m < 4; ++m)
    #pragma unroll
    for (int n = 0; n < 4; ++n)
      #pragma unroll
      for (int j = 0; j < 4; ++j) {
        const int row = bm + wr + m * 16 + g * 4 + j;
        const int col = bn + wc + n * 16 + r;
        const float v = acc[m][n][j];
        if (isb) reinterpret_cast<__bf16*>(Cv)[(size_t)row * N + col] = (__bf16)v;
        else     reinterpret_cast<float*>(Cv)[(size_t)row * N + col] = v;
      }
}

// ---------------------------------------------------------------------------
// RoPE + RMSNorm in-place on Q (heads 0..15) and K (heads 16..19) of QKV.
// ---------------------------------------------------------------------------
__global__ __launch_bounds__(256) void rope_rms(__bf16* __restrict__ qkv,
                                                const float* __restrict__ csF) {
  const int gw = blockIdx.x * 4 + (threadIdx.x >> 6);
  const int lane = threadIdx.x & 63;
  const int head = gw % 20;
  const int m = gw / 20;
  const int t = m & 2047;
  __bf16* p = qkv + (size_t)m * 3072 + head * 128;
  const float x1 = (float)p[lane];
  const float x2 = (float)p[lane + 64];
  const float c = csF[t * 64 + lane];
  const float s = csF[131072 + t * 64 + lane];
  const float y1 = x1 * c + x2 * s;
  const float y2 = x2 * c - x1 * s;
  float ss = y1 * y1 + y2 * y2;
  #pragma unroll
  for (int mk = 32; mk >= 1; mk >>= 1) ss += __shfl_xor(ss, mk, 64);
  const float inv = rsqrtf(ss * (1.0f / 128.0f) + 1.1920929e-7f);
  p[lane] = (__bf16)(y1 * inv);
  p[lane + 64] = (__bf16)(y2 * inv);
}

// ---------------------------------------------------------------------------
// GQA causal flash attention, v2.
// grid (16, B*16): block x pairs q-tiles (x, 31-x) -> uniform 33 kv-tiles.
// 4 waves; wave w owns q rows [qbase + w*16, +16). KVBLK = 64.
// K staged [64][128] linear LDS via gload_lds16 with XOR-swizzled global src;
// V staged from pre-transposed VT as [128 d][64 kv], same swizzle scheme.
// Swapped QK^T (mfma(K,Q)): lane (r,g) holds S[q=r][kv=n*16+g*4+j] -> softmax
// stats are per-lane scalars, reduced over g with 2 shuffles.
// ---------------------------------------------------------------------------
__global__ __launch_bounds__(256) void attn_fwd2(const __bf16* __restrict__ qkv,
                                                 const __bf16* __restrict__ vt,
                                                 __bf16* __restrict__ out) {
  __shared__ __attribute__((aligned(16))) __bf16 Kl[64 * 128];
  __shared__ __attribute__((aligned(16))) __bf16 Vl[128 * 64];
  __shared__ __attribute__((aligned(16))) __bf16 Pl[4][16][72];

  const int tid = threadIdx.x, lane = tid & 63, w = tid >> 6;
  const int r = lane & 15, g = lane >> 4;
  const int b = blockIdx.y >> 4, h = blockIdx.y & 15, kvh = h >> 2;
  const __bf16* Kbase = qkv + (size_t)(b * 2048) * 3072 + 2048 + kvh * 128;
  const __bf16* Vbase = vt + (size_t)((b * 4 + kvh) * 128) * 2048;
  const float scale = 0.08838834764831845f;  // 1/sqrt(128)

  for (int sidx = 0; sidx < 2; ++sidx) {
    const int qt = sidx ? (31 - (int)blockIdx.x) : (int)blockIdx.x;
    const int qbase = qt * 64;
    const int qrow0 = qbase + w * 16;
    const int qpos = qrow0 + r;

    bf16_8 qf[4];
    {
      const __bf16* qp = qkv + (size_t)(b * 2048 + qrow0 + r) * 3072 + h * 128 + g * 8;
      #pragma unroll
      for (int kb = 0; kb < 4; ++kb) qf[kb] = *reinterpret_cast<const bf16_8*>(qp + kb * 32);
    }

    f32x4 accO[8] = {};
    float mst = -1e30f, lst = 0.0f;
    const int nt = qt + 1;

    for (int kt = 0; kt < nt; ++kt) {
      __syncthreads();
      // --- async stage K (64x128) and V^T (128x64), XOR-swizzled sources ---
      #pragma unroll
      for (int i = 0; i < 4; ++i) {
        const int o = tid * 16 + i * 4096;   // byte offset into 16KB tile
        {
          const int krow = o >> 8;           // 256 B per K row
          const int jj = (o >> 4) & 15;      // 16B block in row
          const int gj = (jj & 8) | ((jj ^ krow) & 7);
          gload_lds16(Kbase + (size_t)(kt * 64 + krow) * 3072 + gj * 8, (char*)Kl + o);
        }
        {
          const int d = o >> 7;              // 128 B per V^T row
          const int jj = (o >> 4) & 7;
          const int gj = jj ^ (d & 7);
          gload_lds16(Vbase + (size_t)d * 2048 + kt * 64 + gj * 8, (char*)Vl + o);
        }
      }
      __syncthreads();

      // --- S^T = K Q^T : sacc[n] lane(r,g) = S[q=qpos][kv=kt*64+n*16+g*4+j] ---
      f32x4 sacc[4] = {};
      #pragma unroll
      for (int kb = 0; kb < 4; ++kb) {
        const int jj = kb * 4 + g;
        const int jp = (jj & 8) | ((jj ^ (r & 7)) & 7);
        #pragma unroll
        for (int n = 0; n < 4; ++n) {
          const bf16_8 kf = *reinterpret_cast<const bf16_8*>((char*)Kl + (n * 16 + r) * 256 + jp * 16);
          sacc[n] = __builtin_amdgcn_mfma_f32_16x16x32_bf16(kf, qf[kb], sacc[n], 0, 0, 0);
        }
      }

      // --- online softmax (per-lane scalars, q = qpos) ---
      const bool diag = (kt == qt);
      float p[4][4];
      float pm = -1e30f;
      #pragma unroll
      for (int n = 0; n < 4; ++n)
        #pragma unroll
        for (int j = 0; j < 4; ++j) {
          float s = sacc[n][j] * scale;
          if (diag && (kt * 64 + n * 16 + g * 4 + j > qpos)) s = -1e30f;
          p[n][j] = s;
          pm = fmaxf(pm, s);
        }
      pm = fmaxf(pm, __shfl_xor(pm, 16, 64));
      pm = fmaxf(pm, __shfl_xor(pm, 32, 64));
      const float mn = fmaxf(mst, pm);
      const float alpha = __expf(mst - mn);
      mst = mn;
      float rs = 0.0f;
      #pragma unroll
      for (int n = 0; n < 4; ++n)
        #pragma unroll
        for (int j = 0; j < 4; ++j) {
          p[n][j] = __expf(p[n][j] - mn);
          rs += p[n][j];
        }
      rs += __shfl_xor(rs, 16, 64);
      rs += __shfl_xor(rs, 32, 64);
      lst = lst * alpha + rs;

      // --- P -> per-wave LDS (A-layout relayout) ---
      #pragma unroll
      for (int n = 0; n < 4; ++n) {
        bf16_4 pk;
        #pragma unroll
        for (int j = 0; j < 4; ++j) pk[j] = (__bf16)p[n][j];
        *reinterpret_cast<bf16_4*>(&Pl[w][r][n * 16 + g * 4]) = pk;
      }

      // --- rescale O ---
      float av[4];
      #pragma unroll
      for (int j = 0; j < 4; ++j) av[j] = __shfl(alpha, g * 4 + j, 64);
      #pragma unroll
      for (int dt = 0; dt < 8; ++dt)
        #pragma unroll
        for (int j = 0; j < 4; ++j) accO[dt][j] *= av[j];

      // --- PV: O += P (16x64) @ V (64x128) ---
      #pragma unroll
      for (int half = 0; half < 2; ++half) {
        const bf16_8 pa = *reinterpret_cast<const bf16_8*>(&Pl[w][r][half * 32 + g * 8]);
        #pragma unroll
        for (int dt = 0; dt < 8; ++dt) {
          const int d = dt * 16 + r;
          const bf16_8 vf = *reinterpret_cast<const bf16_8*>((char*)Vl + d * 128 + ((half * 4 + g) ^ (d & 7)) * 16);
          accO[dt] = __builtin_amdgcn_mfma_f32_16x16x32_bf16(pa, vf, accO[dt], 0, 0, 0);
        }
      }
    }

    // --- epilogue: normalize + store ---
    float lv[4];
    #pragma unroll
    for (int j = 0; j < 4; ++j) lv[j] = 1.0f / __shfl(lst, g * 4 + j, 64);
    #pragma unroll
    for (int dt = 0; dt < 8; ++dt)
      #pragma unroll
      for (int j = 0; j < 4; ++j) {
        const int t = qrow0 + g * 4 + j;
        out[(size_t)(b * 2048 + t) * 2048 + h * 128 + dt * 16 + r] = (__bf16)(accO[dt][j] * lv[j]);
      }
  }
}

// ---------------------------------------------------------------------------
extern "C" void kernel_launch(void* const* d_in, const int* in_sizes, int n_in,
                              void* d_out, int out_size, void* d_ws, size_t ws_size,
                              hipStream_t stream) {
  const void* x    = d_in[0];
  const void* cosT = d_in[1];
  const void* sinT = d_in[2];
  const void* W_Q  = d_in[3];
  const void* W_K  = d_in[4];
  const void* W_V  = d_in[5];
  const void* W_O  = d_in[6];

  const int B = 2, T = 2048, C = 2048;
  const int M = B * T;        // 4096
  const int NQKV = 3072;

  char* ws = (char*)d_ws;
  int*    flag = (int*)ws;                       ws += 256;
  float*  csF  = (float*)ws;                     ws += (size_t)2 * 131072 * 4;   // 1 MB
  __bf16* xb   = (__bf16*)ws;                    ws += (size_t)M * C * 2;        // 16.8 MB (dead after gemm1 -> reused for VT)
  __bf16* Wt   = (__bf16*)ws;                    ws += (size_t)NQKV * C * 2;     // 12.6 MB
  __bf16* WOt  = (__bf16*)ws;                    ws += (size_t)C * C * 2;        // 8.4 MB
  __bf16* QKV  = (__bf16*)ws;                    ws += (size_t)M * NQKV * 2;     // 25.2 MB
  __bf16* AO   = (__bf16*)ws;                    ws += (size_t)M * C * 2;        // 16.8 MB
  __bf16* VT   = xb;                             // [2][4][128][2048] = 4 MB, reuses xb

  detect_dtype<<<1, 1, 0, stream>>>(cosT, flag);
  tables_to_f32<<<131072 / 256, 256, 0, stream>>>(cosT, sinT, csF, 131072, flag);
  to_bf16_vec<<<(M * C / 8) / 256, 256, 0, stream>>>(x, xb, M * C / 8, flag);

  dim3 tb(32, 8);
  transpose_to_bf16<<<dim3(2048 / 32, 2048 / 32), tb, 0, stream>>>(W_Q, Wt, 2048, 2048, flag);
  transpose_to_bf16<<<dim3(512 / 32, 2048 / 32), tb, 0, stream>>>(W_K, Wt + (size_t)2048 * 2048, 2048, 512, flag);
  transpose_to_bf16<<<dim3(512 / 32, 2048 / 32), tb, 0, stream>>>(W_V, Wt + (size_t)2560 * 2048, 2048, 512, flag);
  transpose_to_bf16<<<dim3(2048 / 32, 2048 / 32), tb, 0, stream>>>(W_O, WOt, 2048, 2048, flag);

  gemm_bt_t<0><<<dim3(M / 128, NQKV / 128), 256, 0, stream>>>(xb, Wt, QKV, M, NQKV, C, flag);
  rope_rms<<<dim3(M * 20 / 4), 256, 0, stream>>>(QKV, csF);
  vtrans<<<dim3(T / 32, 512 / 32, B), tb, 0, stream>>>(QKV, VT);
  attn_fwd2<<<dim3(16, B * 16), 256, 0, stream>>>(QKV, VT, AO);
  gemm_bt_t<1><<<dim3(M / 128, C / 128), 256, 0, stream>>>(AO, WOt, d_out, M, C, C, flag);
}

// Round 6
// 243.471 us; speedup vs baseline: 2.4805x; 1.1150x over previous
//
#include <hip/hip_runtime.h>
#include <hip/hip_bf16.h>
#include <stdint.h>

typedef __bf16 bf16_4 __attribute__((ext_vector_type(4)));
typedef __bf16 bf16_8 __attribute__((ext_vector_type(8)));
typedef float f32x4 __attribute__((ext_vector_type(4)));

#define AS1 __attribute__((address_space(1)))
#define AS3 __attribute__((address_space(3)))

__device__ __forceinline__ void gload_lds16(const void* g, void* l) {
  __builtin_amdgcn_global_load_lds((const AS1 void*)g, (AS3 void*)l, 16, 0, 0);
}

// ---------------------------------------------------------------------------
// Dtype detection: cos[0][i] == 1.0 exactly. f32 1.0 low halfword = 0x0000,
// bf16 pair (1.0,1.0) = 0x3F803F80 -> low halfword 0x3F80.
// ---------------------------------------------------------------------------
__global__ void detect_dtype(const void* __restrict__ cosT, int* __restrict__ flag) {
  uint32_t w = *reinterpret_cast<const uint32_t*>(cosT);
  *flag = ((w & 0xFFFFu) == 0x3F80u) ? 1 : 0;   // 1 = bf16 buffers, 0 = f32
}

__global__ __launch_bounds__(256) void to_bf16_vec(const void* __restrict__ src,
                                                   __bf16* __restrict__ dst,
                                                   int n8, const int* __restrict__ flag) {
  const int i = blockIdx.x * 256 + threadIdx.x;
  if (i >= n8) return;
  if (*flag) {
    reinterpret_cast<int4*>(dst)[i] = reinterpret_cast<const int4*>(src)[i];
  } else {
    const float4* s = reinterpret_cast<const float4*>(src);
    const float4 a = s[2 * i], b = s[2 * i + 1];
    __bf16 o[8] = {(__bf16)a.x, (__bf16)a.y, (__bf16)a.z, (__bf16)a.w,
                   (__bf16)b.x, (__bf16)b.y, (__bf16)b.z, (__bf16)b.w};
    reinterpret_cast<int4*>(dst)[i] = *reinterpret_cast<int4*>(o);
  }
}

__global__ __launch_bounds__(256) void tables_to_f32(const void* __restrict__ c,
                                                     const void* __restrict__ s,
                                                     float* __restrict__ dst, int n,
                                                     const int* __restrict__ flag) {
  const int i = blockIdx.x * 256 + threadIdx.x;
  if (i >= n) return;
  if (*flag) {
    dst[i]     = (float)reinterpret_cast<const __bf16*>(c)[i];
    dst[n + i] = (float)reinterpret_cast<const __bf16*>(s)[i];
  } else {
    dst[i]     = reinterpret_cast<const float*>(c)[i];
    dst[n + i] = reinterpret_cast<const float*>(s)[i];
  }
}

// ---------------------------------------------------------------------------
// Transpose + convert: src (R x C, f32 or bf16) -> dst (C x R, bf16)
// ---------------------------------------------------------------------------
__global__ void transpose_to_bf16(const void* __restrict__ src, __bf16* __restrict__ dst,
                                  int R, int C, const int* __restrict__ flag) {
  __shared__ __bf16 t[32][33];
  const int c0 = blockIdx.x * 32, r0 = blockIdx.y * 32;
  const bool isb = (*flag != 0);
  #pragma unroll
  for (int i = 0; i < 32; i += 8) {
    const size_t idx = (size_t)(r0 + threadIdx.y + i) * C + c0 + threadIdx.x;
    t[threadIdx.y + i][threadIdx.x] =
        isb ? reinterpret_cast<const __bf16*>(src)[idx]
            : (__bf16)reinterpret_cast<const float*>(src)[idx];
  }
  __syncthreads();
  #pragma unroll
  for (int i = 0; i < 32; i += 8)
    dst[(size_t)(c0 + threadIdx.y + i) * R + r0 + threadIdx.x] = t[threadIdx.x][threadIdx.y + i];
}

// ---------------------------------------------------------------------------
// V slice of QKV -> VT [b][kvh][d][t]  (bf16 tiled transpose)
// ---------------------------------------------------------------------------
__global__ void vtrans(const __bf16* __restrict__ qkv, __bf16* __restrict__ vt) {
  __shared__ __bf16 t[32][33];
  const int b = blockIdx.z;
  const int t0 = blockIdx.x * 32, c0 = blockIdx.y * 32;
  #pragma unroll
  for (int i = 0; i < 32; i += 8)
    t[threadIdx.y + i][threadIdx.x] =
        qkv[(size_t)(b * 2048 + t0 + threadIdx.y + i) * 3072 + 2560 + c0 + threadIdx.x];
  __syncthreads();
  #pragma unroll
  for (int i = 0; i < 32; i += 8)
    vt[(size_t)(b * 512 + c0 + threadIdx.y + i) * 2048 + t0 + threadIdx.x] =
        t[threadIdx.x][threadIdx.y + i];
}

// ---------------------------------------------------------------------------
// GEMM v2: C(MxN) = A(MxK) * Bt(NxK)^T, bf16 in, f32 accum.
// 128x256 tile, BK=64, 8 waves (2Mx4N), per-wave 64x64 (acc[4][4]).
// Double-buffered 96 KiB LDS, XOR-swizzled (both-sides involution),
// 2 phases/K-tile with counted vmcnt (6 gloads/tile in flight) + setprio.
// B LDS rows permuted so staging-issue order == phase read order:
//   lds row rl -> global row ((rl>>5)&3)*64 + ((rl>>7)&1)*32 + (rl&31)
// vmcnt invariant: boundary leaves 2 outstanding (B-bot of next tile),
// mid-tile leaves 3 (new A pair + B-top single).
// ---------------------------------------------------------------------------
template <int DYN>
__global__ __launch_bounds__(512) void gemm8p(const __bf16* __restrict__ A,
                                              const __bf16* __restrict__ Bt,
                                              void* __restrict__ Cv,
                                              int M, int N, int K,
                                              const int* __restrict__ flag) {
  __shared__ __attribute__((aligned(16))) __bf16 As[2][128 * 64];
  __shared__ __attribute__((aligned(16))) __bf16 Bs[2][256 * 64];
  const int tid = threadIdx.x;
  const int lane = tid & 63, w = tid >> 6;
  const int wm = w >> 2, wn = w & 3;
  const int r = lane & 15, g = lane >> 4;
  const int bm = blockIdx.x * 128, bn = blockIdx.y * 256;
  const bool isb = DYN ? (*flag != 0) : true;
  const int NT = K >> 6;

  f32x4 acc[4][4] = {};

#define STA(kt, p, j)                                                              \
  {                                                                                \
    const int o_ = tid * 16 + (j) * 8192;                                          \
    const int row_ = o_ >> 7, blk_ = (o_ >> 4) & 7;                                \
    gload_lds16(A + (size_t)(bm + row_) * K + (kt) * 64 + ((blk_ ^ (row_ & 7)) << 3), \
                (char*)As[p] + o_);                                                \
  }
#define STB(kt, p, j)                                                              \
  {                                                                                \
    const int o_ = tid * 16 + (j) * 8192;                                          \
    const int rl_ = o_ >> 7, blk_ = (o_ >> 4) & 7;                                 \
    const int gr_ = ((rl_ >> 5) & 3) * 64 + ((rl_ >> 7) & 1) * 32 + (rl_ & 31);    \
    gload_lds16(Bt + (size_t)(bn + gr_) * K + (kt) * 64 + ((blk_ ^ (rl_ & 7)) << 3), \
                (char*)Bs[p] + o_);                                                \
  }

  // prologue: stage tile 0 -> buf 0 (order: A0 A1 B0 B1 B2 B3)
  STA(0, 0, 0); STA(0, 0, 1);
  STB(0, 0, 0); STB(0, 0, 1); STB(0, 0, 2); STB(0, 0, 3);
  asm volatile("s_waitcnt vmcnt(2)\ns_barrier" ::: "memory");

  for (int kt = 0; kt < NT; ++kt) {
    const int cur = kt & 1, nxt = cur ^ 1;
    const bool pf = (kt + 1 < NT);
    const char* Ac = (const char*)As[cur];
    const char* Bc = (const char*)Bs[cur];

    // ---- phase A: all A-frags + B cols 0..31 ----
    bf16_8 af[4][2], bf[2][2];
    #pragma unroll
    for (int m = 0; m < 4; ++m)
      #pragma unroll
      for (int kk = 0; kk < 2; ++kk) {
        const int row = wm * 64 + m * 16 + r;
        af[m][kk] = *reinterpret_cast<const bf16_8*>(
            Ac + row * 128 + (((kk * 4 + g) ^ (row & 7)) << 4));
      }
    #pragma unroll
    for (int n = 0; n < 2; ++n)
      #pragma unroll
      for (int kk = 0; kk < 2; ++kk) {
        const int rl = wn * 32 + n * 16 + r;
        bf[n][kk] = *reinterpret_cast<const bf16_8*>(
            Bc + rl * 128 + (((kk * 4 + g) ^ (rl & 7)) << 4));
      }
    if (pf) { STA(kt + 1, nxt, 0); STA(kt + 1, nxt, 1); STB(kt + 1, nxt, 0); }
    __builtin_amdgcn_s_barrier();
    __builtin_amdgcn_s_setprio(1);
    #pragma unroll
    for (int kk = 0; kk < 2; ++kk)
      #pragma unroll
      for (int m = 0; m < 4; ++m)
        #pragma unroll
        for (int n = 0; n < 2; ++n)
          acc[m][n] = __builtin_amdgcn_mfma_f32_16x16x32_bf16(af[m][kk], bf[n][kk], acc[m][n], 0, 0, 0);
    __builtin_amdgcn_s_setprio(0);
    if (pf) asm volatile("s_waitcnt vmcnt(3)\ns_barrier" ::: "memory");
    else    asm volatile("s_waitcnt vmcnt(0)\ns_barrier" ::: "memory");

    // ---- phase B: B cols 32..63 ----
    bf16_8 bg[2][2];
    #pragma unroll
    for (int n = 0; n < 2; ++n)
      #pragma unroll
      for (int kk = 0; kk < 2; ++kk) {
        const int rl = 128 + wn * 32 + n * 16 + r;
        bg[n][kk] = *reinterpret_cast<const bf16_8*>(
            Bc + rl * 128 + (((kk * 4 + g) ^ (rl & 7)) << 4));
      }
    if (pf) { STB(kt + 1, nxt, 1); STB(kt + 1, nxt, 2); STB(kt + 1, nxt, 3); }
    __builtin_amdgcn_s_barrier();
    __builtin_amdgcn_s_setprio(1);
    #pragma unroll
    for (int kk = 0; kk < 2; ++kk)
      #pragma unroll
      for (int m = 0; m < 4; ++m)
        #pragma unroll
        for (int n = 0; n < 2; ++n)
          acc[m][n + 2] = __builtin_amdgcn_mfma_f32_16x16x32_bf16(af[m][kk], bg[n][kk], acc[m][n + 2], 0, 0, 0);
    __builtin_amdgcn_s_setprio(0);
    if (pf) asm volatile("s_waitcnt vmcnt(2)\ns_barrier" ::: "memory");
    else    asm volatile("s_waitcnt vmcnt(0)\ns_barrier" ::: "memory");
  }
#undef STA
#undef STB

  #pragma unroll
  for (int m = 0; m < 4; ++m)
    #pragma unroll
    for (int n = 0; n < 4; ++n)
      #pragma unroll
      for (int j = 0; j < 4; ++j) {
        const int row = bm + wm * 64 + m * 16 + g * 4 + j;
        const int col = bn + wn * 64 + n * 16 + r;
        const float v = acc[m][n][j];
        if (isb) reinterpret_cast<__bf16*>(Cv)[(size_t)row * N + col] = (__bf16)v;
        else     reinterpret_cast<float*>(Cv)[(size_t)row * N + col] = v;
      }
}

// ---------------------------------------------------------------------------
// RoPE + RMSNorm in-place on Q (heads 0..15) and K (heads 16..19) of QKV.
// ---------------------------------------------------------------------------
__global__ __launch_bounds__(256) void rope_rms(__bf16* __restrict__ qkv,
                                                const float* __restrict__ csF) {
  const int gw = blockIdx.x * 4 + (threadIdx.x >> 6);
  const int lane = threadIdx.x & 63;
  const int head = gw % 20;
  const int m = gw / 20;
  const int t = m & 2047;
  __bf16* p = qkv + (size_t)m * 3072 + head * 128;
  const float x1 = (float)p[lane];
  const float x2 = (float)p[lane + 64];
  const float c = csF[t * 64 + lane];
  const float s = csF[131072 + t * 64 + lane];
  const float y1 = x1 * c + x2 * s;
  const float y2 = x2 * c - x1 * s;
  float ss = y1 * y1 + y2 * y2;
  #pragma unroll
  for (int mk = 32; mk >= 1; mk >>= 1) ss += __shfl_xor(ss, mk, 64);
  const float inv = rsqrtf(ss * (1.0f / 128.0f) + 1.1920929e-7f);
  p[lane] = (__bf16)(y1 * inv);
  p[lane + 64] = (__bf16)(y2 * inv);
}

// ---------------------------------------------------------------------------
// GQA causal flash attention, v2 (unchanged from round 5 — passed, fast).
// ---------------------------------------------------------------------------
__global__ __launch_bounds__(256) void attn_fwd2(const __bf16* __restrict__ qkv,
                                                 const __bf16* __restrict__ vt,
                                                 __bf16* __restrict__ out) {
  __shared__ __attribute__((aligned(16))) __bf16 Kl[64 * 128];
  __shared__ __attribute__((aligned(16))) __bf16 Vl[128 * 64];
  __shared__ __attribute__((aligned(16))) __bf16 Pl[4][16][72];

  const int tid = threadIdx.x, lane = tid & 63, w = tid >> 6;
  const int r = lane & 15, g = lane >> 4;
  const int b = blockIdx.y >> 4, h = blockIdx.y & 15, kvh = h >> 2;
  const __bf16* Kbase = qkv + (size_t)(b * 2048) * 3072 + 2048 + kvh * 128;
  const __bf16* Vbase = vt + (size_t)((b * 4 + kvh) * 128) * 2048;
  const float scale = 0.08838834764831845f;  // 1/sqrt(128)

  for (int sidx = 0; sidx < 2; ++sidx) {
    const int qt = sidx ? (31 - (int)blockIdx.x) : (int)blockIdx.x;
    const int qbase = qt * 64;
    const int qrow0 = qbase + w * 16;
    const int qpos = qrow0 + r;

    bf16_8 qf[4];
    {
      const __bf16* qp = qkv + (size_t)(b * 2048 + qrow0 + r) * 3072 + h * 128 + g * 8;
      #pragma unroll
      for (int kb = 0; kb < 4; ++kb) qf[kb] = *reinterpret_cast<const bf16_8*>(qp + kb * 32);
    }

    f32x4 accO[8] = {};
    float mst = -1e30f, lst = 0.0f;
    const int nt = qt + 1;

    for (int kt = 0; kt < nt; ++kt) {
      __syncthreads();
      #pragma unroll
      for (int i = 0; i < 4; ++i) {
        const int o = tid * 16 + i * 4096;
        {
          const int krow = o >> 8;
          const int jj = (o >> 4) & 15;
          const int gj = (jj & 8) | ((jj ^ krow) & 7);
          gload_lds16(Kbase + (size_t)(kt * 64 + krow) * 3072 + gj * 8, (char*)Kl + o);
        }
        {
          const int d = o >> 7;
          const int jj = (o >> 4) & 7;
          const int gj = jj ^ (d & 7);
          gload_lds16(Vbase + (size_t)d * 2048 + kt * 64 + gj * 8, (char*)Vl + o);
        }
      }
      __syncthreads();

      f32x4 sacc[4] = {};
      #pragma unroll
      for (int kb = 0; kb < 4; ++kb) {
        const int jj = kb * 4 + g;
        const int jp = (jj & 8) | ((jj ^ (r & 7)) & 7);
        #pragma unroll
        for (int n = 0; n < 4; ++n) {
          const bf16_8 kf = *reinterpret_cast<const bf16_8*>((char*)Kl + (n * 16 + r) * 256 + jp * 16);
          sacc[n] = __builtin_amdgcn_mfma_f32_16x16x32_bf16(kf, qf[kb], sacc[n], 0, 0, 0);
        }
      }

      const bool diag = (kt == qt);
      float p[4][4];
      float pm = -1e30f;
      #pragma unroll
      for (int n = 0; n < 4; ++n)
        #pragma unroll
        for (int j = 0; j < 4; ++j) {
          float s = sacc[n][j] * scale;
          if (diag && (kt * 64 + n * 16 + g * 4 + j > qpos)) s = -1e30f;
          p[n][j] = s;
          pm = fmaxf(pm, s);
        }
      pm = fmaxf(pm, __shfl_xor(pm, 16, 64));
      pm = fmaxf(pm, __shfl_xor(pm, 32, 64));
      const float mn = fmaxf(mst, pm);
      const float alpha = __expf(mst - mn);
      mst = mn;
      float rs = 0.0f;
      #pragma unroll
      for (int n = 0; n < 4; ++n)
        #pragma unroll
        for (int j = 0; j < 4; ++j) {
          p[n][j] = __expf(p[n][j] - mn);
          rs += p[n][j];
        }
      rs += __shfl_xor(rs, 16, 64);
      rs += __shfl_xor(rs, 32, 64);
      lst = lst * alpha + rs;

      #pragma unroll
      for (int n = 0; n < 4; ++n) {
        bf16_4 pk;
        #pragma unroll
        for (int j = 0; j < 4; ++j) pk[j] = (__bf16)p[n][j];
        *reinterpret_cast<bf16_4*>(&Pl[w][r][n * 16 + g * 4]) = pk;
      }

      float av[4];
      #pragma unroll
      for (int j = 0; j < 4; ++j) av[j] = __shfl(alpha, g * 4 + j, 64);
      #pragma unroll
      for (int dt = 0; dt < 8; ++dt)
        #pragma unroll
        for (int j = 0; j < 4; ++j) accO[dt][j] *= av[j];

      #pragma unroll
      for (int half = 0; half < 2; ++half) {
        const bf16_8 pa = *reinterpret_cast<const bf16_8*>(&Pl[w][r][half * 32 + g * 8]);
        #pragma unroll
        for (int dt = 0; dt < 8; ++dt) {
          const int d = dt * 16 + r;
          const bf16_8 vf = *reinterpret_cast<const bf16_8*>((char*)Vl + d * 128 + ((half * 4 + g) ^ (d & 7)) * 16);
          accO[dt] = __builtin_amdgcn_mfma_f32_16x16x32_bf16(pa, vf, accO[dt], 0, 0, 0);
        }
      }
    }

    float lv[4];
    #pragma unroll
    for (int j = 0; j < 4; ++j) lv[j] = 1.0f / __shfl(lst, g * 4 + j, 64);
    #pragma unroll
    for (int dt = 0; dt < 8; ++dt)
      #pragma unroll
      for (int j = 0; j < 4; ++j) {
        const int t = qrow0 + g * 4 + j;
        out[(size_t)(b * 2048 + t) * 2048 + h * 128 + dt * 16 + r] = (__bf16)(accO[dt][j] * lv[j]);
      }
  }
}

// ---------------------------------------------------------------------------
extern "C" void kernel_launch(void* const* d_in, const int* in_sizes, int n_in,
                              void* d_out, int out_size, void* d_ws, size_t ws_size,
                              hipStream_t stream) {
  const void* x    = d_in[0];
  const void* cosT = d_in[1];
  const void* sinT = d_in[2];
  const void* W_Q  = d_in[3];
  const void* W_K  = d_in[4];
  const void* W_V  = d_in[5];
  const void* W_O  = d_in[6];

  const int B = 2, T = 2048, C = 2048;
  const int M = B * T;        // 4096
  const int NQKV = 3072;

  char* ws = (char*)d_ws;
  int*    flag = (int*)ws;                       ws += 256;
  float*  csF  = (float*)ws;                     ws += (size_t)2 * 131072 * 4;   // 1 MB
  __bf16* xb   = (__bf16*)ws;                    ws += (size_t)M * C * 2;        // 16.8 MB (dead after gemm1 -> reused for VT)
  __bf16* Wt   = (__bf16*)ws;                    ws += (size_t)NQKV * C * 2;     // 12.6 MB
  __bf16* WOt  = (__bf16*)ws;                    ws += (size_t)C * C * 2;        // 8.4 MB
  __bf16* QKV  = (__bf16*)ws;                    ws += (size_t)M * NQKV * 2;     // 25.2 MB
  __bf16* AO   = (__bf16*)ws;                    ws += (size_t)M * C * 2;        // 16.8 MB
  __bf16* VT   = xb;                             // [2][4][128][2048] = 4 MB, reuses xb

  detect_dtype<<<1, 1, 0, stream>>>(cosT, flag);
  tables_to_f32<<<131072 / 256, 256, 0, stream>>>(cosT, sinT, csF, 131072, flag);
  to_bf16_vec<<<(M * C / 8) / 256, 256, 0, stream>>>(x, xb, M * C / 8, flag);

  dim3 tb(32, 8);
  transpose_to_bf16<<<dim3(2048 / 32, 2048 / 32), tb, 0, stream>>>(W_Q, Wt, 2048, 2048, flag);
  transpose_to_bf16<<<dim3(512 / 32, 2048 / 32), tb, 0, stream>>>(W_K, Wt + (size_t)2048 * 2048, 2048, 512, flag);
  transpose_to_bf16<<<dim3(512 / 32, 2048 / 32), tb, 0, stream>>>(W_V, Wt + (size_t)2560 * 2048, 2048, 512, flag);
  transpose_to_bf16<<<dim3(2048 / 32, 2048 / 32), tb, 0, stream>>>(W_O, WOt, 2048, 2048, flag);

  gemm8p<0><<<dim3(M / 128, NQKV / 256), 512, 0, stream>>>(xb, Wt, QKV, M, NQKV, C, flag);
  rope_rms<<<dim3(M * 20 / 4), 256, 0, stream>>>(QKV, csF);
  vtrans<<<dim3(T / 32, 512 / 32, B), tb, 0, stream>>>(QKV, VT);
  attn_fwd2<<<dim3(16, B * 16), 256, 0, stream>>>(QKV, VT, AO);
  gemm8p<1><<<dim3(M / 128, C / 256), 512, 0, stream>>>(AO, WOt, d_out, M, C, C, flag);
}

// Round 7
// 231.659 us; speedup vs baseline: 2.6070x; 1.0510x over previous
//
#include <hip/hip_runtime.h>
#include <hip/hip_bf16.h>
#include <stdint.h>

typedef __bf16 bf16_4 __attribute__((ext_vector_type(4)));
typedef __bf16 bf16_8 __attribute__((ext_vector_type(8)));
typedef float f32x4 __attribute__((ext_vector_type(4)));

#define AS1 __attribute__((address_space(1)))
#define AS3 __attribute__((address_space(3)))

__device__ __forceinline__ void gload_lds16(const void* g, void* l) {
  __builtin_amdgcn_global_load_lds((const AS1 void*)g, (AS3 void*)l, 16, 0, 0);
}

// ---------------------------------------------------------------------------
// Dtype detection: cos[0][i] == 1.0 exactly. f32 1.0 low halfword = 0x0000,
// bf16 pair (1.0,1.0) = 0x3F803F80 -> low halfword 0x3F80.
// ---------------------------------------------------------------------------
__global__ void detect_dtype(const void* __restrict__ cosT, int* __restrict__ flag) {
  uint32_t w = *reinterpret_cast<const uint32_t*>(cosT);
  *flag = ((w & 0xFFFFu) == 0x3F80u) ? 1 : 0;   // 1 = bf16 buffers, 0 = f32
}

__global__ __launch_bounds__(256) void to_bf16_vec(const void* __restrict__ src,
                                                   __bf16* __restrict__ dst,
                                                   int n8, const int* __restrict__ flag) {
  const int i = blockIdx.x * 256 + threadIdx.x;
  if (i >= n8) return;
  if (*flag) {
    reinterpret_cast<int4*>(dst)[i] = reinterpret_cast<const int4*>(src)[i];
  } else {
    const float4* s = reinterpret_cast<const float4*>(src);
    const float4 a = s[2 * i], b = s[2 * i + 1];
    __bf16 o[8] = {(__bf16)a.x, (__bf16)a.y, (__bf16)a.z, (__bf16)a.w,
                   (__bf16)b.x, (__bf16)b.y, (__bf16)b.z, (__bf16)b.w};
    reinterpret_cast<int4*>(dst)[i] = *reinterpret_cast<int4*>(o);
  }
}

__global__ __launch_bounds__(256) void tables_to_f32(const void* __restrict__ c,
                                                     const void* __restrict__ s,
                                                     float* __restrict__ dst, int n,
                                                     const int* __restrict__ flag) {
  const int i = blockIdx.x * 256 + threadIdx.x;
  if (i >= n) return;
  if (*flag) {
    dst[i]     = (float)reinterpret_cast<const __bf16*>(c)[i];
    dst[n + i] = (float)reinterpret_cast<const __bf16*>(s)[i];
  } else {
    dst[i]     = reinterpret_cast<const float*>(c)[i];
    dst[n + i] = reinterpret_cast<const float*>(s)[i];
  }
}

// ---------------------------------------------------------------------------
// Fused weight transpose+convert: WQ|WK|WV -> Wt (3072x2048), WO -> WOt.
// All srcs are 2048 x cols. grid (160, 64), block (32,8).
//   bx <  64: WQ col-tile bx      -> Wt rows 32*bx
//   bx <  80: WK col-tile bx-64   -> Wt rows 2048*... offset 2048*2048
//   bx <  96: WV col-tile bx-80   -> Wt offset 2560*2048
//   else    : WO col-tile bx-96   -> WOt
// ---------------------------------------------------------------------------
__global__ void transpose_all(const void* __restrict__ WQ, const void* __restrict__ WK,
                              const void* __restrict__ WV, const void* __restrict__ WO,
                              __bf16* __restrict__ Wt, __bf16* __restrict__ WOt,
                              const int* __restrict__ flag) {
  __shared__ __bf16 t[32][33];
  const int bx = blockIdx.x;
  const void* src;
  __bf16* dst;
  int C, c0;
  if (bx < 64)      { src = WQ; dst = Wt;                          C = 2048; c0 = bx * 32; }
  else if (bx < 80) { src = WK; dst = Wt + (size_t)2048 * 2048;    C = 512;  c0 = (bx - 64) * 32; }
  else if (bx < 96) { src = WV; dst = Wt + (size_t)2560 * 2048;    C = 512;  c0 = (bx - 80) * 32; }
  else              { src = WO; dst = WOt;                         C = 2048; c0 = (bx - 96) * 32; }
  const int r0 = blockIdx.y * 32;
  const bool isb = (*flag != 0);
  #pragma unroll
  for (int i = 0; i < 32; i += 8) {
    const size_t idx = (size_t)(r0 + threadIdx.y + i) * C + c0 + threadIdx.x;
    t[threadIdx.y + i][threadIdx.x] =
        isb ? reinterpret_cast<const __bf16*>(src)[idx]
            : (__bf16)reinterpret_cast<const float*>(src)[idx];
  }
  __syncthreads();
  #pragma unroll
  for (int i = 0; i < 32; i += 8)
    dst[(size_t)(c0 + threadIdx.y + i) * 2048 + r0 + threadIdx.x] = t[threadIdx.x][threadIdx.y + i];
}

// ---------------------------------------------------------------------------
// V slice of QKV -> VT [b][kvh][d][t]  (bf16 tiled transpose)
// ---------------------------------------------------------------------------
__global__ void vtrans(const __bf16* __restrict__ qkv, __bf16* __restrict__ vt) {
  __shared__ __bf16 t[32][33];
  const int b = blockIdx.z;
  const int t0 = blockIdx.x * 32, c0 = blockIdx.y * 32;
  #pragma unroll
  for (int i = 0; i < 32; i += 8)
    t[threadIdx.y + i][threadIdx.x] =
        qkv[(size_t)(b * 2048 + t0 + threadIdx.y + i) * 3072 + 2560 + c0 + threadIdx.x];
  __syncthreads();
  #pragma unroll
  for (int i = 0; i < 32; i += 8)
    vt[(size_t)(b * 512 + c0 + threadIdx.y + i) * 2048 + t0 + threadIdx.x] =
        t[threadIdx.x][threadIdx.y + i];
}

// ---------------------------------------------------------------------------
// GEMM v2 (unchanged from round 6): 128x256 tile, BK=64, 8 waves, dbuf LDS,
// XOR-swizzle, 2 phases/K-tile with counted vmcnt + setprio.
// ---------------------------------------------------------------------------
template <int DYN>
__global__ __launch_bounds__(512) void gemm8p(const __bf16* __restrict__ A,
                                              const __bf16* __restrict__ Bt,
                                              void* __restrict__ Cv,
                                              int M, int N, int K,
                                              const int* __restrict__ flag) {
  __shared__ __attribute__((aligned(16))) __bf16 As[2][128 * 64];
  __shared__ __attribute__((aligned(16))) __bf16 Bs[2][256 * 64];
  const int tid = threadIdx.x;
  const int lane = tid & 63, w = tid >> 6;
  const int wm = w >> 2, wn = w & 3;
  const int r = lane & 15, g = lane >> 4;
  const int bm = blockIdx.x * 128, bn = blockIdx.y * 256;
  const bool isb = DYN ? (*flag != 0) : true;
  const int NT = K >> 6;

  f32x4 acc[4][4] = {};

#define STA(kt, p, j)                                                              \
  {                                                                                \
    const int o_ = tid * 16 + (j) * 8192;                                          \
    const int row_ = o_ >> 7, blk_ = (o_ >> 4) & 7;                                \
    gload_lds16(A + (size_t)(bm + row_) * K + (kt) * 64 + ((blk_ ^ (row_ & 7)) << 3), \
                (char*)As[p] + o_);                                                \
  }
#define STB(kt, p, j)                                                              \
  {                                                                                \
    const int o_ = tid * 16 + (j) * 8192;                                          \
    const int rl_ = o_ >> 7, blk_ = (o_ >> 4) & 7;                                 \
    const int gr_ = ((rl_ >> 5) & 3) * 64 + ((rl_ >> 7) & 1) * 32 + (rl_ & 31);    \
    gload_lds16(Bt + (size_t)(bn + gr_) * K + (kt) * 64 + ((blk_ ^ (rl_ & 7)) << 3), \
                (char*)Bs[p] + o_);                                                \
  }

  STA(0, 0, 0); STA(0, 0, 1);
  STB(0, 0, 0); STB(0, 0, 1); STB(0, 0, 2); STB(0, 0, 3);
  asm volatile("s_waitcnt vmcnt(2)\ns_barrier" ::: "memory");

  for (int kt = 0; kt < NT; ++kt) {
    const int cur = kt & 1, nxt = cur ^ 1;
    const bool pf = (kt + 1 < NT);
    const char* Ac = (const char*)As[cur];
    const char* Bc = (const char*)Bs[cur];

    bf16_8 af[4][2], bf[2][2];
    #pragma unroll
    for (int m = 0; m < 4; ++m)
      #pragma unroll
      for (int kk = 0; kk < 2; ++kk) {
        const int row = wm * 64 + m * 16 + r;
        af[m][kk] = *reinterpret_cast<const bf16_8*>(
            Ac + row * 128 + (((kk * 4 + g) ^ (row & 7)) << 4));
      }
    #pragma unroll
    for (int n = 0; n < 2; ++n)
      #pragma unroll
      for (int kk = 0; kk < 2; ++kk) {
        const int rl = wn * 32 + n * 16 + r;
        bf[n][kk] = *reinterpret_cast<const bf16_8*>(
            Bc + rl * 128 + (((kk * 4 + g) ^ (rl & 7)) << 4));
      }
    if (pf) { STA(kt + 1, nxt, 0); STA(kt + 1, nxt, 1); STB(kt + 1, nxt, 0); }
    __builtin_amdgcn_s_barrier();
    __builtin_amdgcn_s_setprio(1);
    #pragma unroll
    for (int kk = 0; kk < 2; ++kk)
      #pragma unroll
      for (int m = 0; m < 4; ++m)
        #pragma unroll
        for (int n = 0; n < 2; ++n)
          acc[m][n] = __builtin_amdgcn_mfma_f32_16x16x32_bf16(af[m][kk], bf[n][kk], acc[m][n], 0, 0, 0);
    __builtin_amdgcn_s_setprio(0);
    if (pf) asm volatile("s_waitcnt vmcnt(3)\ns_barrier" ::: "memory");
    else    asm volatile("s_waitcnt vmcnt(0)\ns_barrier" ::: "memory");

    bf16_8 bg[2][2];
    #pragma unroll
    for (int n = 0; n < 2; ++n)
      #pragma unroll
      for (int kk = 0; kk < 2; ++kk) {
        const int rl = 128 + wn * 32 + n * 16 + r;
        bg[n][kk] = *reinterpret_cast<const bf16_8*>(
            Bc + rl * 128 + (((kk * 4 + g) ^ (rl & 7)) << 4));
      }
    if (pf) { STB(kt + 1, nxt, 1); STB(kt + 1, nxt, 2); STB(kt + 1, nxt, 3); }
    __builtin_amdgcn_s_barrier();
    __builtin_amdgcn_s_setprio(1);
    #pragma unroll
    for (int kk = 0; kk < 2; ++kk)
      #pragma unroll
      for (int m = 0; m < 4; ++m)
        #pragma unroll
        for (int n = 0; n < 2; ++n)
          acc[m][n + 2] = __builtin_amdgcn_mfma_f32_16x16x32_bf16(af[m][kk], bg[n][kk], acc[m][n + 2], 0, 0, 0);
    __builtin_amdgcn_s_setprio(0);
    if (pf) asm volatile("s_waitcnt vmcnt(2)\ns_barrier" ::: "memory");
    else    asm volatile("s_waitcnt vmcnt(0)\ns_barrier" ::: "memory");
  }
#undef STA
#undef STB

  #pragma unroll
  for (int m = 0; m < 4; ++m)
    #pragma unroll
    for (int n = 0; n < 4; ++n)
      #pragma unroll
      for (int j = 0; j < 4; ++j) {
        const int row = bm + wm * 64 + m * 16 + g * 4 + j;
        const int col = bn + wn * 64 + n * 16 + r;
        const float v = acc[m][n][j];
        if (isb) reinterpret_cast<__bf16*>(Cv)[(size_t)row * N + col] = (__bf16)v;
        else     reinterpret_cast<float*>(Cv)[(size_t)row * N + col] = v;
      }
}

// ---------------------------------------------------------------------------
// RoPE + RMSNorm in-place on Q (heads 0..15) and K (heads 16..19) of QKV.
// ---------------------------------------------------------------------------
__global__ __launch_bounds__(256) void rope_rms(__bf16* __restrict__ qkv,
                                                const float* __restrict__ csF) {
  const int gw = blockIdx.x * 4 + (threadIdx.x >> 6);
  const int lane = threadIdx.x & 63;
  const int head = gw % 20;
  const int m = gw / 20;
  const int t = m & 2047;
  __bf16* p = qkv + (size_t)m * 3072 + head * 128;
  const float x1 = (float)p[lane];
  const float x2 = (float)p[lane + 64];
  const float c = csF[t * 64 + lane];
  const float s = csF[131072 + t * 64 + lane];
  const float y1 = x1 * c + x2 * s;
  const float y2 = x2 * c - x1 * s;
  float ss = y1 * y1 + y2 * y2;
  #pragma unroll
  for (int mk = 32; mk >= 1; mk >>= 1) ss += __shfl_xor(ss, mk, 64);
  const float inv = rsqrtf(ss * (1.0f / 128.0f) + 1.1920929e-7f);
  p[lane] = (__bf16)(y1 * inv);
  p[lane + 64] = (__bf16)(y2 * inv);
}

// ---------------------------------------------------------------------------
// GQA causal flash attention, v3.
// 1-D grid of 512, XCD-aware: grp = lid&7 = (b,kvh) so all 64 blocks sharing
// one K/V stream land on one XCD (KV 2MB fits 4MB L2). inner = lid>>3:
// head-in-group (inner&3), q-pair (inner>>2) paired (x, 31-x).
// Double-buffered K/V staging: STAGE(kt+1) issued before compute(kt),
// one vmcnt(0)+barrier per tile. Softmax in exp2 domain, defer-max THR=12.
// ---------------------------------------------------------------------------
__global__ __launch_bounds__(256) void attn_fwd3(const __bf16* __restrict__ qkv,
                                                 const __bf16* __restrict__ vt,
                                                 __bf16* __restrict__ out) {
  __shared__ __attribute__((aligned(16))) __bf16 Kl[2][64 * 128];
  __shared__ __attribute__((aligned(16))) __bf16 Vl[2][128 * 64];
  __shared__ __attribute__((aligned(16))) __bf16 Pl[4][16][72];

  const int tid = threadIdx.x, lane = tid & 63, w = tid >> 6;
  const int r = lane & 15, g = lane >> 4;
  const int lid = blockIdx.x;
  const int grp = lid & 7, inner = lid >> 3;
  const int b = grp >> 2, kvh = grp & 3;
  const int h = kvh * 4 + (inner & 3);
  const int xq = inner >> 2;                 // 0..15 pair index
  const __bf16* Kbase = qkv + (size_t)(b * 2048) * 3072 + 2048 + kvh * 128;
  const __bf16* Vbase = vt + (size_t)((b * 4 + kvh) * 128) * 2048;
  const float sc2 = 0.08838834764831845f * 1.44269504f;  // scale * log2(e)

#define STAGE(kt, p)                                                            \
  {                                                                             \
    _Pragma("unroll")                                                           \
    for (int i_ = 0; i_ < 4; ++i_) {                                            \
      const int o_ = tid * 16 + i_ * 4096;                                      \
      const int krow_ = o_ >> 8;                                                \
      const int jj_ = (o_ >> 4) & 15;                                           \
      const int gj_ = (jj_ & 8) | ((jj_ ^ krow_) & 7);                          \
      gload_lds16(Kbase + (size_t)((kt) * 64 + krow_) * 3072 + gj_ * 8,         \
                  (char*)Kl[p] + o_);                                           \
      const int d_ = o_ >> 7;                                                   \
      const int j2_ = (o_ >> 4) & 7;                                            \
      const int g2_ = j2_ ^ (d_ & 7);                                           \
      gload_lds16(Vbase + (size_t)d_ * 2048 + (kt) * 64 + g2_ * 8,              \
                  (char*)Vl[p] + o_);                                           \
    }                                                                           \
  }

  for (int sidx = 0; sidx < 2; ++sidx) {
    const int qt = sidx ? (31 - xq) : xq;
    const int qrow0 = qt * 64 + w * 16;
    const int qpos = qrow0 + r;

    bf16_8 qf[4];
    {
      const __bf16* qp = qkv + (size_t)(b * 2048 + qrow0 + r) * 3072 + h * 128 + g * 8;
      #pragma unroll
      for (int kb = 0; kb < 4; ++kb) qf[kb] = *reinterpret_cast<const bf16_8*>(qp + kb * 32);
    }

    f32x4 accO[8] = {};
    float mst = -1e30f, lst = 0.0f;
    const int nt = qt + 1;

    STAGE(0, 0);
    asm volatile("s_waitcnt vmcnt(0)" ::: "memory");
    __syncthreads();

    for (int kt = 0; kt < nt; ++kt) {
      const int cur = kt & 1;
      if (kt + 1 < nt) STAGE(kt + 1, cur ^ 1);
      const char* Kc = (const char*)Kl[cur];
      const char* Vc = (const char*)Vl[cur];

      // --- S^T = K Q^T (exp2 domain) ---
      f32x4 sacc[4] = {};
      #pragma unroll
      for (int kb = 0; kb < 4; ++kb) {
        const int jj = kb * 4 + g;
        const int jp = (jj & 8) | ((jj ^ (r & 7)) & 7);
        #pragma unroll
        for (int n = 0; n < 4; ++n) {
          const bf16_8 kf = *reinterpret_cast<const bf16_8*>(Kc + (n * 16 + r) * 256 + jp * 16);
          sacc[n] = __builtin_amdgcn_mfma_f32_16x16x32_bf16(kf, qf[kb], sacc[n], 0, 0, 0);
        }
      }

      // --- online softmax, per-lane scalars ---
      float p[4][4];
      float pm = -1e30f;
      #pragma unroll
      for (int n = 0; n < 4; ++n)
        #pragma unroll
        for (int j = 0; j < 4; ++j) {
          float s = sacc[n][j] * sc2;
          p[n][j] = s;
          pm = fmaxf(pm, s);
        }
      if (kt == qt) {   // diagonal tile: causal mask
        pm = -1e30f;
        #pragma unroll
        for (int n = 0; n < 4; ++n)
          #pragma unroll
          for (int j = 0; j < 4; ++j) {
            if (kt * 64 + n * 16 + g * 4 + j > qpos) p[n][j] = -1e30f;
            pm = fmaxf(pm, p[n][j]);
          }
      }
      pm = fmaxf(pm, __shfl_xor(pm, 16, 64));
      pm = fmaxf(pm, __shfl_xor(pm, 32, 64));

      float mn;
      const bool defer = __all(pm - mst <= 12.0f);
      if (defer) {
        mn = mst;
      } else {
        mn = fmaxf(mst, pm);
        const float alpha = exp2f(mst - mn);
        mst = mn;
        lst *= alpha;
        float av[4];
        #pragma unroll
        for (int j = 0; j < 4; ++j) av[j] = __shfl(alpha, g * 4 + j, 64);
        #pragma unroll
        for (int dt = 0; dt < 8; ++dt)
          #pragma unroll
          for (int j = 0; j < 4; ++j) accO[dt][j] *= av[j];
      }
      float rs = 0.0f;
      #pragma unroll
      for (int n = 0; n < 4; ++n)
        #pragma unroll
        for (int j = 0; j < 4; ++j) {
          p[n][j] = exp2f(p[n][j] - mn);
          rs += p[n][j];
        }
      rs += __shfl_xor(rs, 16, 64);
      rs += __shfl_xor(rs, 32, 64);
      lst += rs;

      // --- P -> per-wave LDS (A-layout relayout) ---
      #pragma unroll
      for (int n = 0; n < 4; ++n) {
        bf16_4 pk;
        #pragma unroll
        for (int j = 0; j < 4; ++j) pk[j] = (__bf16)p[n][j];
        *reinterpret_cast<bf16_4*>(&Pl[w][r][n * 16 + g * 4]) = pk;
      }

      // --- PV: O += P (16x64) @ V (64x128) ---
      #pragma unroll
      for (int half = 0; half < 2; ++half) {
        const bf16_8 pa = *reinterpret_cast<const bf16_8*>(&Pl[w][r][half * 32 + g * 8]);
        #pragma unroll
        for (int dt = 0; dt < 8; ++dt) {
          const int d = dt * 16 + r;
          const bf16_8 vf = *reinterpret_cast<const bf16_8*>(Vc + d * 128 + ((half * 4 + g) ^ (d & 7)) * 16);
          accO[dt] = __builtin_amdgcn_mfma_f32_16x16x32_bf16(pa, vf, accO[dt], 0, 0, 0);
        }
      }

      asm volatile("s_waitcnt vmcnt(0)" ::: "memory");
      __syncthreads();
    }

    // --- epilogue: normalize + store ---
    float lv[4];
    #pragma unroll
    for (int j = 0; j < 4; ++j) lv[j] = 1.0f / __shfl(lst, g * 4 + j, 64);
    #pragma unroll
    for (int dt = 0; dt < 8; ++dt)
      #pragma unroll
      for (int j = 0; j < 4; ++j) {
        const int t = qrow0 + g * 4 + j;
        out[(size_t)(b * 2048 + t) * 2048 + h * 128 + dt * 16 + r] = (__bf16)(accO[dt][j] * lv[j]);
      }
  }
#undef STAGE
}

// ---------------------------------------------------------------------------
extern "C" void kernel_launch(void* const* d_in, const int* in_sizes, int n_in,
                              void* d_out, int out_size, void* d_ws, size_t ws_size,
                              hipStream_t stream) {
  const void* x    = d_in[0];
  const void* cosT = d_in[1];
  const void* sinT = d_in[2];
  const void* W_Q  = d_in[3];
  const void* W_K  = d_in[4];
  const void* W_V  = d_in[5];
  const void* W_O  = d_in[6];

  const int B = 2, T = 2048, C = 2048;
  const int M = B * T;        // 4096
  const int NQKV = 3072;

  char* ws = (char*)d_ws;
  int*    flag = (int*)ws;                       ws += 256;
  float*  csF  = (float*)ws;                     ws += (size_t)2 * 131072 * 4;   // 1 MB
  __bf16* xb   = (__bf16*)ws;                    ws += (size_t)M * C * 2;        // 16.8 MB (dead after gemm1 -> reused for VT)
  __bf16* Wt   = (__bf16*)ws;                    ws += (size_t)NQKV * C * 2;     // 12.6 MB
  __bf16* WOt  = (__bf16*)ws;                    ws += (size_t)C * C * 2;        // 8.4 MB
  __bf16* QKV  = (__bf16*)ws;                    ws += (size_t)M * NQKV * 2;     // 25.2 MB
  __bf16* AO   = (__bf16*)ws;                    ws += (size_t)M * C * 2;        // 16.8 MB
  __bf16* VT   = xb;                             // [2][4][128][2048] = 4 MB, reuses xb

  detect_dtype<<<1, 1, 0, stream>>>(cosT, flag);
  tables_to_f32<<<131072 / 256, 256, 0, stream>>>(cosT, sinT, csF, 131072, flag);
  to_bf16_vec<<<(M * C / 8) / 256, 256, 0, stream>>>(x, xb, M * C / 8, flag);

  transpose_all<<<dim3(160, 64), dim3(32, 8), 0, stream>>>(W_Q, W_K, W_V, W_O, Wt, WOt, flag);

  gemm8p<0><<<dim3(M / 128, NQKV / 256), 512, 0, stream>>>(xb, Wt, QKV, M, NQKV, C, flag);
  rope_rms<<<dim3(M * 20 / 4), 256, 0, stream>>>(QKV, csF);
  vtrans<<<dim3(T / 32, 512 / 32, B), dim3(32, 8), 0, stream>>>(QKV, VT);
  attn_fwd3<<<dim3(512), 256, 0, stream>>>(QKV, VT, AO);
  gemm8p<1><<<dim3(M / 128, C / 256), 512, 0, stream>>>(AO, WOt, d_out, M, C, C, flag);
}

// Round 9
// 230.029 us; speedup vs baseline: 2.6255x; 1.0071x over previous
//
#include <hip/hip_runtime.h>
#include <hip/hip_bf16.h>
#include <stdint.h>

typedef __bf16 bf16_4 __attribute__((ext_vector_type(4)));
typedef __bf16 bf16_8 __attribute__((ext_vector_type(8)));
typedef float f32x4 __attribute__((ext_vector_type(4)));

#define AS1 __attribute__((address_space(1)))
#define AS3 __attribute__((address_space(3)))

__device__ __forceinline__ void gload_lds16(const void* g, void* l) {
  __builtin_amdgcn_global_load_lds((const AS1 void*)g, (AS3 void*)l, 16, 0, 0);
}

// ---------------------------------------------------------------------------
// Dtype detection: cos[0][i] == 1.0 exactly. f32 1.0 low halfword = 0x0000,
// bf16 pair (1.0,1.0) = 0x3F803F80 -> low halfword 0x3F80.
// ---------------------------------------------------------------------------
__global__ void detect_dtype(const void* __restrict__ cosT, int* __restrict__ flag) {
  uint32_t w = *reinterpret_cast<const uint32_t*>(cosT);
  *flag = ((w & 0xFFFFu) == 0x3F80u) ? 1 : 0;   // 1 = bf16 buffers, 0 = f32
}

__global__ __launch_bounds__(256) void to_bf16_vec(const void* __restrict__ src,
                                                   __bf16* __restrict__ dst,
                                                   int n8, const int* __restrict__ flag) {
  const int i = blockIdx.x * 256 + threadIdx.x;
  if (i >= n8) return;
  if (*flag) {
    reinterpret_cast<int4*>(dst)[i] = reinterpret_cast<const int4*>(src)[i];
  } else {
    const float4* s = reinterpret_cast<const float4*>(src);
    const float4 a = s[2 * i], b = s[2 * i + 1];
    __bf16 o[8] = {(__bf16)a.x, (__bf16)a.y, (__bf16)a.z, (__bf16)a.w,
                   (__bf16)b.x, (__bf16)b.y, (__bf16)b.z, (__bf16)b.w};
    reinterpret_cast<int4*>(dst)[i] = *reinterpret_cast<int4*>(o);
  }
}

__global__ __launch_bounds__(256) void tables_to_f32(const void* __restrict__ c,
                                                     const void* __restrict__ s,
                                                     float* __restrict__ dst, int n,
                                                     const int* __restrict__ flag) {
  const int i = blockIdx.x * 256 + threadIdx.x;
  if (i >= n) return;
  if (*flag) {
    dst[i]     = (float)reinterpret_cast<const __bf16*>(c)[i];
    dst[n + i] = (float)reinterpret_cast<const __bf16*>(s)[i];
  } else {
    dst[i]     = reinterpret_cast<const float*>(c)[i];
    dst[n + i] = reinterpret_cast<const float*>(s)[i];
  }
}

// ---------------------------------------------------------------------------
// Fused weight transpose+convert: WQ|WK|WV -> Wt (3072x2048), WO -> WOt.
// ---------------------------------------------------------------------------
__global__ void transpose_all(const void* __restrict__ WQ, const void* __restrict__ WK,
                              const void* __restrict__ WV, const void* __restrict__ WO,
                              __bf16* __restrict__ Wt, __bf16* __restrict__ WOt,
                              const int* __restrict__ flag) {
  __shared__ __bf16 t[32][33];
  const int bx = blockIdx.x;
  const void* src;
  __bf16* dst;
  int C, c0;
  if (bx < 64)      { src = WQ; dst = Wt;                          C = 2048; c0 = bx * 32; }
  else if (bx < 80) { src = WK; dst = Wt + (size_t)2048 * 2048;    C = 512;  c0 = (bx - 64) * 32; }
  else if (bx < 96) { src = WV; dst = Wt + (size_t)2560 * 2048;    C = 512;  c0 = (bx - 80) * 32; }
  else              { src = WO; dst = WOt;                         C = 2048; c0 = (bx - 96) * 32; }
  const int r0 = blockIdx.y * 32;
  const bool isb = (*flag != 0);
  #pragma unroll
  for (int i = 0; i < 32; i += 8) {
    const size_t idx = (size_t)(r0 + threadIdx.y + i) * C + c0 + threadIdx.x;
    t[threadIdx.y + i][threadIdx.x] =
        isb ? reinterpret_cast<const __bf16*>(src)[idx]
            : (__bf16)reinterpret_cast<const float*>(src)[idx];
  }
  __syncthreads();
  #pragma unroll
  for (int i = 0; i < 32; i += 8)
    dst[(size_t)(c0 + threadIdx.y + i) * 2048 + r0 + threadIdx.x] = t[threadIdx.x][threadIdx.y + i];
}

// ---------------------------------------------------------------------------
// V slice of QKV -> VT [b][kvh][d][t]  (bf16 tiled transpose)
// ---------------------------------------------------------------------------
__global__ void vtrans(const __bf16* __restrict__ qkv, __bf16* __restrict__ vt) {
  __shared__ __bf16 t[32][33];
  const int b = blockIdx.z;
  const int t0 = blockIdx.x * 32, c0 = blockIdx.y * 32;
  #pragma unroll
  for (int i = 0; i < 32; i += 8)
    t[threadIdx.y + i][threadIdx.x] =
        qkv[(size_t)(b * 2048 + t0 + threadIdx.y + i) * 3072 + 2560 + c0 + threadIdx.x];
  __syncthreads();
  #pragma unroll
  for (int i = 0; i < 32; i += 8)
    vt[(size_t)(b * 512 + c0 + threadIdx.y + i) * 2048 + t0 + threadIdx.x] =
        t[threadIdx.x][threadIdx.y + i];
}

// ---------------------------------------------------------------------------
// GEMM (unchanged): 128x256 tile, BK=64, 8 waves, dbuf LDS, XOR-swizzle,
// 2 phases/K-tile with counted vmcnt + setprio.
// ---------------------------------------------------------------------------
template <int DYN>
__global__ __launch_bounds__(512) void gemm8p(const __bf16* __restrict__ A,
                                              const __bf16* __restrict__ Bt,
                                              void* __restrict__ Cv,
                                              int M, int N, int K,
                                              const int* __restrict__ flag) {
  __shared__ __attribute__((aligned(16))) __bf16 As[2][128 * 64];
  __shared__ __attribute__((aligned(16))) __bf16 Bs[2][256 * 64];
  const int tid = threadIdx.x;
  const int lane = tid & 63, w = tid >> 6;
  const int wm = w >> 2, wn = w & 3;
  const int r = lane & 15, g = lane >> 4;
  const int bm = blockIdx.x * 128, bn = blockIdx.y * 256;
  const bool isb = DYN ? (*flag != 0) : true;
  const int NT = K >> 6;

  f32x4 acc[4][4] = {};

#define STA(kt, p, j)                                                              \
  {                                                                                \
    const int o_ = tid * 16 + (j) * 8192;                                          \
    const int row_ = o_ >> 7, blk_ = (o_ >> 4) & 7;                                \
    gload_lds16(A + (size_t)(bm + row_) * K + (kt) * 64 + ((blk_ ^ (row_ & 7)) << 3), \
                (char*)As[p] + o_);                                                \
  }
#define STB(kt, p, j)                                                              \
  {                                                                                \
    const int o_ = tid * 16 + (j) * 8192;                                          \
    const int rl_ = o_ >> 7, blk_ = (o_ >> 4) & 7;                                 \
    const int gr_ = ((rl_ >> 5) & 3) * 64 + ((rl_ >> 7) & 1) * 32 + (rl_ & 31);    \
    gload_lds16(Bt + (size_t)(bn + gr_) * K + (kt) * 64 + ((blk_ ^ (rl_ & 7)) << 3), \
                (char*)Bs[p] + o_);                                                \
  }

  STA(0, 0, 0); STA(0, 0, 1);
  STB(0, 0, 0); STB(0, 0, 1); STB(0, 0, 2); STB(0, 0, 3);
  asm volatile("s_waitcnt vmcnt(2)\ns_barrier" ::: "memory");

  for (int kt = 0; kt < NT; ++kt) {
    const int cur = kt & 1, nxt = cur ^ 1;
    const bool pf = (kt + 1 < NT);
    const char* Ac = (const char*)As[cur];
    const char* Bc = (const char*)Bs[cur];

    bf16_8 af[4][2], bf[2][2];
    #pragma unroll
    for (int m = 0; m < 4; ++m)
      #pragma unroll
      for (int kk = 0; kk < 2; ++kk) {
        const int row = wm * 64 + m * 16 + r;
        af[m][kk] = *reinterpret_cast<const bf16_8*>(
            Ac + row * 128 + (((kk * 4 + g) ^ (row & 7)) << 4));
      }
    #pragma unroll
    for (int n = 0; n < 2; ++n)
      #pragma unroll
      for (int kk = 0; kk < 2; ++kk) {
        const int rl = wn * 32 + n * 16 + r;
        bf[n][kk] = *reinterpret_cast<const bf16_8*>(
            Bc + rl * 128 + (((kk * 4 + g) ^ (rl & 7)) << 4));
      }
    if (pf) { STA(kt + 1, nxt, 0); STA(kt + 1, nxt, 1); STB(kt + 1, nxt, 0); }
    __builtin_amdgcn_s_barrier();
    __builtin_amdgcn_s_setprio(1);
    #pragma unroll
    for (int kk = 0; kk < 2; ++kk)
      #pragma unroll
      for (int m = 0; m < 4; ++m)
        #pragma unroll
        for (int n = 0; n < 2; ++n)
          acc[m][n] = __builtin_amdgcn_mfma_f32_16x16x32_bf16(af[m][kk], bf[n][kk], acc[m][n], 0, 0, 0);
    __builtin_amdgcn_s_setprio(0);
    if (pf) asm volatile("s_waitcnt vmcnt(3)\ns_barrier" ::: "memory");
    else    asm volatile("s_waitcnt vmcnt(0)\ns_barrier" ::: "memory");

    bf16_8 bg[2][2];
    #pragma unroll
    for (int n = 0; n < 2; ++n)
      #pragma unroll
      for (int kk = 0; kk < 2; ++kk) {
        const int rl = 128 + wn * 32 + n * 16 + r;
        bg[n][kk] = *reinterpret_cast<const bf16_8*>(
            Bc + rl * 128 + (((kk * 4 + g) ^ (rl & 7)) << 4));
      }
    if (pf) { STB(kt + 1, nxt, 1); STB(kt + 1, nxt, 2); STB(kt + 1, nxt, 3); }
    __builtin_amdgcn_s_barrier();
    __builtin_amdgcn_s_setprio(1);
    #pragma unroll
    for (int kk = 0; kk < 2; ++kk)
      #pragma unroll
      for (int m = 0; m < 4; ++m)
        #pragma unroll
        for (int n = 0; n < 2; ++n)
          acc[m][n + 2] = __builtin_amdgcn_mfma_f32_16x16x32_bf16(af[m][kk], bg[n][kk], acc[m][n + 2], 0, 0, 0);
    __builtin_amdgcn_s_setprio(0);
    if (pf) asm volatile("s_waitcnt vmcnt(2)\ns_barrier" ::: "memory");
    else    asm volatile("s_waitcnt vmcnt(0)\ns_barrier" ::: "memory");
  }
#undef STA
#undef STB

  #pragma unroll
  for (int m = 0; m < 4; ++m)
    #pragma unroll
    for (int n = 0; n < 4; ++n)
      #pragma unroll
      for (int j = 0; j < 4; ++j) {
        const int row = bm + wm * 64 + m * 16 + g * 4 + j;
        const int col = bn + wn * 64 + n * 16 + r;
        const float v = acc[m][n][j];
        if (isb) reinterpret_cast<__bf16*>(Cv)[(size_t)row * N + col] = (__bf16)v;
        else     reinterpret_cast<float*>(Cv)[(size_t)row * N + col] = v;
      }
}

// ---------------------------------------------------------------------------
// RoPE + RMSNorm in-place on Q (heads 0..15) and K (heads 16..19) of QKV.
// ---------------------------------------------------------------------------
__global__ __launch_bounds__(256) void rope_rms(__bf16* __restrict__ qkv,
                                                const float* __restrict__ csF) {
  const int gw = blockIdx.x * 4 + (threadIdx.x >> 6);
  const int lane = threadIdx.x & 63;
  const int head = gw % 20;
  const int m = gw / 20;
  const int t = m & 2047;
  __bf16* p = qkv + (size_t)m * 3072 + head * 128;
  const float x1 = (float)p[lane];
  const float x2 = (float)p[lane + 64];
  const float c = csF[t * 64 + lane];
  const float s = csF[131072 + t * 64 + lane];
  const float y1 = x1 * c + x2 * s;
  const float y2 = x2 * c - x1 * s;
  float ss = y1 * y1 + y2 * y2;
  #pragma unroll
  for (int mk = 32; mk >= 1; mk >>= 1) ss += __shfl_xor(ss, mk, 64);
  const float inv = rsqrtf(ss * (1.0f / 128.0f) + 1.1920929e-7f);
  p[lane] = (__bf16)(y1 * inv);
  p[lane + 64] = (__bf16)(y2 * inv);
}

// ---------------------------------------------------------------------------
// GQA causal flash attention, v4: dual q-tile in flight.
// Grid 512 (1-D), XCD-aware: grp = lid&7 = (b,kvh) -> one K/V stream per XCD.
// inner = lid>>3: h = kvh*4 + (inner&3), x = inner>>2 (0..15).
// Each block owns q-tiles qtA = x (nA = x+1 kv-tiles) and qtB = 31-x
// (nB = 32-x). One kv loop over 0..nB-1 stages K/V ONCE and feeds both
// tiles (A active while kt < nA; nA+nB = 33 uniform). Two independent
// QK/softmax/PV chains per iteration -> ILP hides exp2/VALU latency.
// Double-buffered staging, exp2-domain softmax, defer-max THR=12.
// ---------------------------------------------------------------------------
__global__ __launch_bounds__(256) void attn_fwd4(const __bf16* __restrict__ qkv,
                                                 const __bf16* __restrict__ vt,
                                                 __bf16* __restrict__ out) {
  __shared__ __attribute__((aligned(16))) __bf16 Kl[2][64 * 128];
  __shared__ __attribute__((aligned(16))) __bf16 Vl[2][128 * 64];
  __shared__ __attribute__((aligned(16))) __bf16 Pl[4][16][72];

  const int tid = threadIdx.x, lane = tid & 63, w = tid >> 6;
  const int r = lane & 15, g = lane >> 4;
  const int lid = blockIdx.x;
  const int grp = lid & 7, inner = lid >> 3;
  const int b = grp >> 2, kvh = grp & 3;
  const int h = kvh * 4 + (inner & 3);
  const int x = inner >> 2;                  // 0..15
  const int qtA = x, qtB = 31 - x;
  const int nA = qtA + 1, nB = qtB + 1;      // nA + nB = 33
  const __bf16* Kbase = qkv + (size_t)(b * 2048) * 3072 + 2048 + kvh * 128;
  const __bf16* Vbase = vt + (size_t)((b * 4 + kvh) * 128) * 2048;
  const float sc2 = 0.08838834764831845f * 1.44269504f;  // scale * log2(e)

#define STAGE(kt, p)                                                            \
  {                                                                             \
    _Pragma("unroll")                                                           \
    for (int i_ = 0; i_ < 4; ++i_) {                                            \
      const int o_ = tid * 16 + i_ * 4096;                                      \
      const int krow_ = o_ >> 8;                                                \
      const int jj_ = (o_ >> 4) & 15;                                           \
      const int gj_ = (jj_ & 8) | ((jj_ ^ krow_) & 7);                          \
      gload_lds16(Kbase + (size_t)((kt) * 64 + krow_) * 3072 + gj_ * 8,         \
                  (char*)Kl[p] + o_);                                           \
      const int d_ = o_ >> 7;                                                   \
      const int j2_ = (o_ >> 4) & 7;                                            \
      const int g2_ = j2_ ^ (d_ & 7);                                           \
      gload_lds16(Vbase + (size_t)d_ * 2048 + (kt) * 64 + g2_ * 8,              \
                  (char*)Vl[p] + o_);                                           \
    }                                                                           \
  }

// one q-tile's QK -> softmax -> P -> PV against the staged (Kc, Vc)
#define TILE(qt_, qf_, acc_, mst_, lst_)                                        \
  do {                                                                          \
    f32x4 sacc[4] = {};                                                         \
    _Pragma("unroll")                                                           \
    for (int kb = 0; kb < 4; ++kb) {                                            \
      const int jj = kb * 4 + g;                                                \
      const int jp = (jj & 8) | ((jj ^ (r & 7)) & 7);                           \
      _Pragma("unroll")                                                         \
      for (int n = 0; n < 4; ++n) {                                             \
        const bf16_8 kf = *reinterpret_cast<const bf16_8*>(Kc + (n * 16 + r) * 256 + jp * 16); \
        sacc[n] = __builtin_amdgcn_mfma_f32_16x16x32_bf16(kf, qf_[kb], sacc[n], 0, 0, 0); \
      }                                                                         \
    }                                                                           \
    float p[4][4];                                                              \
    float pm = -1e30f;                                                          \
    _Pragma("unroll")                                                           \
    for (int n = 0; n < 4; ++n)                                                 \
      _Pragma("unroll")                                                         \
      for (int j = 0; j < 4; ++j) {                                             \
        float s = sacc[n][j] * sc2;                                             \
        p[n][j] = s;                                                            \
        pm = fmaxf(pm, s);                                                      \
      }                                                                         \
    if (kt == (qt_)) {                                                          \
      const int qpos_ = (qt_) * 64 + w * 16 + r;                                \
      pm = -1e30f;                                                              \
      _Pragma("unroll")                                                         \
      for (int n = 0; n < 4; ++n)                                               \
        _Pragma("unroll")                                                       \
        for (int j = 0; j < 4; ++j) {                                           \
          if (kt * 64 + n * 16 + g * 4 + j > qpos_) p[n][j] = -1e30f;           \
          pm = fmaxf(pm, p[n][j]);                                              \
        }                                                                       \
    }                                                                           \
    pm = fmaxf(pm, __shfl_xor(pm, 16, 64));                                     \
    pm = fmaxf(pm, __shfl_xor(pm, 32, 64));                                     \
    float mn = mst_;                                                            \
    if (!__all(pm - mst_ <= 12.0f)) {                                           \
      mn = fmaxf(mst_, pm);                                                     \
      const float alpha = exp2f(mst_ - mn);                                     \
      mst_ = mn;                                                                \
      lst_ *= alpha;                                                            \
      float av[4];                                                              \
      _Pragma("unroll")                                                         \
      for (int j = 0; j < 4; ++j) av[j] = __shfl(alpha, g * 4 + j, 64);         \
      _Pragma("unroll")                                                         \
      for (int dt = 0; dt < 8; ++dt)                                            \
        _Pragma("unroll")                                                       \
        for (int j = 0; j < 4; ++j) acc_[dt][j] *= av[j];                       \
    }                                                                           \
    float rs = 0.0f;                                                            \
    _Pragma("unroll")                                                           \
    for (int n = 0; n < 4; ++n)                                                 \
      _Pragma("unroll")                                                         \
      for (int j = 0; j < 4; ++j) {                                             \
        p[n][j] = exp2f(p[n][j] - mn);                                          \
        rs += p[n][j];                                                          \
      }                                                                         \
    rs += __shfl_xor(rs, 16, 64);                                               \
    rs += __shfl_xor(rs, 32, 64);                                               \
    lst_ += rs;                                                                 \
    _Pragma("unroll")                                                           \
    for (int n = 0; n < 4; ++n) {                                               \
      bf16_4 pk;                                                                \
      _Pragma("unroll")                                                         \
      for (int j = 0; j < 4; ++j) pk[j] = (__bf16)p[n][j];                      \
      *reinterpret_cast<bf16_4*>(&Pl[w][r][n * 16 + g * 4]) = pk;               \
    }                                                                           \
    _Pragma("unroll")                                                           \
    for (int half = 0; half < 2; ++half) {                                      \
      const bf16_8 pa = *reinterpret_cast<const bf16_8*>(&Pl[w][r][half * 32 + g * 8]); \
      _Pragma("unroll")                                                         \
      for (int dt = 0; dt < 8; ++dt) {                                          \
        const int d = dt * 16 + r;                                              \
        const bf16_8 vf = *reinterpret_cast<const bf16_8*>(Vc + d * 128 + ((half * 4 + g) ^ (d & 7)) * 16); \
        acc_[dt] = __builtin_amdgcn_mfma_f32_16x16x32_bf16(pa, vf, acc_[dt], 0, 0, 0); \
      }                                                                         \
    }                                                                           \
  } while (0)

  // Q fragments for both tiles
  bf16_8 qfA[4], qfB[4];
  {
    const __bf16* qpA = qkv + (size_t)(b * 2048 + qtA * 64 + w * 16 + r) * 3072 + h * 128 + g * 8;
    const __bf16* qpB = qkv + (size_t)(b * 2048 + qtB * 64 + w * 16 + r) * 3072 + h * 128 + g * 8;
    #pragma unroll
    for (int kb = 0; kb < 4; ++kb) {
      qfA[kb] = *reinterpret_cast<const bf16_8*>(qpA + kb * 32);
      qfB[kb] = *reinterpret_cast<const bf16_8*>(qpB + kb * 32);
    }
  }

  f32x4 accA[8] = {}, accB[8] = {};
  float mstA = -1e30f, lstA = 0.0f, mstB = -1e30f, lstB = 0.0f;

  STAGE(0, 0);
  asm volatile("s_waitcnt vmcnt(0)" ::: "memory");
  __syncthreads();

  for (int kt = 0; kt < nB; ++kt) {
    const int cur = kt & 1;
    if (kt + 1 < nB) STAGE(kt + 1, cur ^ 1);
    const char* Kc = (const char*)Kl[cur];
    const char* Vc = (const char*)Vl[cur];

    if (kt < nA) TILE(qtA, qfA, accA, mstA, lstA);
    TILE(qtB, qfB, accB, mstB, lstB);

    asm volatile("s_waitcnt vmcnt(0)" ::: "memory");
    __syncthreads();
  }

  // --- epilogue: normalize + store both tiles ---
  {
    float lv[4];
    #pragma unroll
    for (int j = 0; j < 4; ++j) lv[j] = 1.0f / __shfl(lstA, g * 4 + j, 64);
    #pragma unroll
    for (int dt = 0; dt < 8; ++dt)
      #pragma unroll
      for (int j = 0; j < 4; ++j) {
        const int t = qtA * 64 + w * 16 + g * 4 + j;
        out[(size_t)(b * 2048 + t) * 2048 + h * 128 + dt * 16 + r] = (__bf16)(accA[dt][j] * lv[j]);
      }
  }
  {
    float lv[4];
    #pragma unroll
    for (int j = 0; j < 4; ++j) lv[j] = 1.0f / __shfl(lstB, g * 4 + j, 64);
    #pragma unroll
    for (int dt = 0; dt < 8; ++dt)
      #pragma unroll
      for (int j = 0; j < 4; ++j) {
        const int t = qtB * 64 + w * 16 + g * 4 + j;
        out[(size_t)(b * 2048 + t) * 2048 + h * 128 + dt * 16 + r] = (__bf16)(accB[dt][j] * lv[j]);
      }
  }
#undef STAGE
#undef TILE
}

// ---------------------------------------------------------------------------
extern "C" void kernel_launch(void* const* d_in, const int* in_sizes, int n_in,
                              void* d_out, int out_size, void* d_ws, size_t ws_size,
                              hipStream_t stream) {
  const void* x    = d_in[0];
  const void* cosT = d_in[1];
  const void* sinT = d_in[2];
  const void* W_Q  = d_in[3];
  const void* W_K  = d_in[4];
  const void* W_V  = d_in[5];
  const void* W_O  = d_in[6];

  const int B = 2, T = 2048, C = 2048;
  const int M = B * T;        // 4096
  const int NQKV = 3072;

  char* ws = (char*)d_ws;
  int*    flag = (int*)ws;                       ws += 256;
  float*  csF  = (float*)ws;                     ws += (size_t)2 * 131072 * 4;   // 1 MB
  __bf16* xb   = (__bf16*)ws;                    ws += (size_t)M * C * 2;        // 16.8 MB (dead after gemm1 -> reused for VT)
  __bf16* Wt   = (__bf16*)ws;                    ws += (size_t)NQKV * C * 2;     // 12.6 MB
  __bf16* WOt  = (__bf16*)ws;                    ws += (size_t)C * C * 2;        // 8.4 MB
  __bf16* QKV  = (__bf16*)ws;                    ws += (size_t)M * NQKV * 2;     // 25.2 MB
  __bf16* AO   = (__bf16*)ws;                    ws += (size_t)M * C * 2;        // 16.8 MB
  __bf16* VT   = xb;                             // [2][4][128][2048] = 4 MB, reuses xb

  detect_dtype<<<1, 1, 0, stream>>>(cosT, flag);
  tables_to_f32<<<131072 / 256, 256, 0, stream>>>(cosT, sinT, csF, 131072, flag);
  to_bf16_vec<<<(M * C / 8) / 256, 256, 0, stream>>>(x, xb, M * C / 8, flag);

  transpose_all<<<dim3(160, 64), dim3(32, 8), 0, stream>>>(W_Q, W_K, W_V, W_O, Wt, WOt, flag);

  gemm8p<0><<<dim3(M / 128, NQKV / 256), 512, 0, stream>>>(xb, Wt, QKV, M, NQKV, C, flag);
  rope_rms<<<dim3(M * 20 / 4), 256, 0, stream>>>(QKV, csF);
  vtrans<<<dim3(T / 32, 512 / 32, B), dim3(32, 8), 0, stream>>>(QKV, VT);
  attn_fwd4<<<dim3(512), 256, 0, stream>>>(QKV, VT, AO);
  gemm8p<1><<<dim3(M / 128, C / 256), 512, 0, stream>>>(AO, WOt, d_out, M, C, C, flag);
}